// Round 1
// baseline (308.425 us; speedup 1.0000x reference)
//
#include <hip/hip_runtime.h>

typedef unsigned short u16;
typedef unsigned int u32;
typedef __attribute__((ext_vector_type(8))) short short8;
typedef __attribute__((ext_vector_type(4))) float float4v;

#define RS 8192     // node-range size (32KB LDS int counters)
#define RSH 13
#define GP 8        // partition chunks per col-chunk

__device__ inline float bf16_lo(u32 v) { return __uint_as_float(v << 16); }
__device__ inline float bf16_hi(u32 v) { return __uint_as_float(v & 0xFFFF0000u); }

__device__ inline u16 f32_to_bf16(float f) {
    u32 u = __float_as_uint(f);
    u32 r = u + 0x7FFFu + ((u >> 16) & 1u);   // round-to-nearest-even
    return (u16)(r >> 16);
}

// ---------------- P0: partition edges by col-range (pairs) and src-range (srcp) -------------
__global__ __launch_bounds__(256) void partition_kernel(const int* __restrict__ er,
                                                        const int* __restrict__ ec,
                                                        u32* __restrict__ pairs,
                                                        u16* __restrict__ srcp,
                                                        int* __restrict__ rof,
                                                        int* __restrict__ srof,
                                                        int E, int cpb, int NR) {
    __shared__ int cnt[16], scnt[16];
    const int k = blockIdx.x, tid = threadIdx.x;
    const int e0 = k * cpb, e1 = min(e0 + cpb, E);
    if (tid < 16) { cnt[tid] = 0; scnt[tid] = 0; }
    __syncthreads();
    for (int e = e0 + tid; e < e1; e += 256) {
        atomicAdd(&cnt[ec[e] >> RSH], 1);
        atomicAdd(&scnt[er[e] >> RSH], 1);
    }
    __syncthreads();
    if (tid == 0) {
        int run = 0;
        for (int r = 0; r < NR; r++) { int c = cnt[r]; rof[k*16 + r] = run; cnt[r] = run; run += c; }
        rof[k*16 + NR] = run;
        run = 0;
        for (int r = 0; r < NR; r++) { int c = scnt[r]; srof[k*16 + r] = run; scnt[r] = run; run += c; }
        srof[k*16 + NR] = run;
    }
    __syncthreads();
    const size_t base = (size_t)k * cpb;
    for (int e = e0 + tid; e < e1; e += 256) {
        int s = er[e], c = ec[e];
        int slot = atomicAdd(&cnt[c >> RSH], 1);
        pairs[base + slot] = ((u32)s << 16) | (u32)c;
        int slot2 = atomicAdd(&scnt[s >> RSH], 1);
        srcp[base + slot2] = (u16)s;
    }
}

// ---------------- col histogram over partitioned pairs -> pcol u16 --------------------------
__global__ __launch_bounds__(256) void colhist_kernel(const u32* __restrict__ pairs,
                                                      const int* __restrict__ rof,
                                                      u16* __restrict__ pcol,
                                                      int N, int cpb) {
    __shared__ alignas(16) int hist[RS];
    const int kc = blockIdx.x, r = blockIdx.y, tid = threadIdx.x;
    const int rbase = r << RSH;
    const int rcount = min(RS, N - rbase);
    for (int j = tid; j < RS / 4; j += 256) ((int4*)hist)[j] = make_int4(0, 0, 0, 0);
    __syncthreads();
    for (int g = 0; g < GP; g++) {
        const int kp = kc * GP + g;
        const size_t base = (size_t)kp * cpb;
        const int s = rof[kp*16 + r], e = rof[kp*16 + r + 1];
        for (int i = s + tid; i < e; i += 256) {
            u32 p = pairs[base + i];
            atomicAdd(&hist[(int)(p & 0xFFFFu) - rbase], 1);
        }
    }
    __syncthreads();
    for (int j = tid; j < rcount; j += 256)
        pcol[(size_t)kc * N + rbase + j] = (u16)hist[j];
}

// ---------------- deg histogram over partitioned srcs -> pdeg u16 ---------------------------
__global__ __launch_bounds__(256) void deghist_kernel(const u16* __restrict__ srcp,
                                                      const int* __restrict__ srof,
                                                      u16* __restrict__ pdeg,
                                                      int N, int cpb, int GPD) {
    __shared__ alignas(16) int hist[RS];
    const int kd = blockIdx.x, r = blockIdx.y, tid = threadIdx.x;
    const int rbase = r << RSH;
    const int rcount = min(RS, N - rbase);
    for (int j = tid; j < RS / 4; j += 256) ((int4*)hist)[j] = make_int4(0, 0, 0, 0);
    __syncthreads();
    for (int g = 0; g < GPD; g++) {
        const int kp = kd * GPD + g;
        const size_t base = (size_t)kp * cpb;
        const int s = srof[kp*16 + r], e = srof[kp*16 + r + 1];
        for (int i = s + tid; i < e; i += 256)
            atomicAdd(&hist[(int)srcp[base + i] - rbase], 1);
    }
    __syncthreads();
    for (int j = tid; j < rcount; j += 256)
        pdeg[(size_t)kd * N + rbase + j] = (u16)hist[j];
}

// ---------------- chunk scan: 8 threads/node, register-batched loads + shfl prefix ----------
__global__ __launch_bounds__(256) void chunk_scan_kernel(u16* __restrict__ pcol,
                                                         const u16* __restrict__ pdeg,
                                                         int* __restrict__ totals,
                                                         float* __restrict__ dis,
                                                         int N, int NC, int NCD) {
    const int gid = blockIdx.x * 256 + threadIdx.x;
    const int node = gid >> 3;
    const int t = threadIdx.x & 7;
    if (node >= N) return;
    const int per = NC >> 3;     // <= 16 (NC multiple of 16)
    const int k0 = t * per;
    int vals[16];
    int sum = 0;
#pragma unroll
    for (int j = 0; j < 16; j++) {      // independent guarded loads -> one latency round trip
        int v = 0;
        if (j < per) v = pcol[(size_t)(k0 + j) * N + node];
        vals[j] = v;
        sum += v;
    }
    int inc = sum;                       // inclusive scan across the node's 8 lanes
#pragma unroll
    for (int d = 1; d < 8; d <<= 1) {
        int v = __shfl_up(inc, d, 8);    // wave-uniform; sources within same 8-group
        if (t >= d) inc += v;
    }
    int run = inc - sum;                 // exclusive base for this thread's chunk span
#pragma unroll
    for (int j = 0; j < 16; j++) {
        if (j < per) {
            pcol[(size_t)(k0 + j) * N + node] = (u16)run;
            run += vals[j];
        }
    }
    if (t == 7) totals[node] = inc;      // lane 7's inclusive = node total

    const int perd = NCD >> 3;           // <= 8 (NCD multiple of 8)
    int s = 0;
#pragma unroll
    for (int j = 0; j < 8; j++) {
        if (j < perd) s += pdeg[(size_t)(t * perd + j) * N + node];
    }
    s += __shfl_xor(s, 1);
    s += __shfl_xor(s, 2);
    s += __shfl_xor(s, 4);
    if (t == 0) dis[node] = rsqrtf((float)(s + 1));  // +1 self loop; always > 0
}

// Phase A': per-256-node block sums of totals.
__global__ __launch_bounds__(256) void bsum_kernel(const int* __restrict__ totals,
                                                   int* __restrict__ bsum, int N) {
    __shared__ int red[256];
    int i = blockIdx.x * 256 + threadIdx.x;
    red[threadIdx.x] = (i < N) ? totals[i] : 0;
    __syncthreads();
#pragma unroll
    for (int off = 128; off > 0; off >>= 1) {
        if (threadIdx.x < off) red[threadIdx.x] += red[threadIdx.x + off];
        __syncthreads();
    }
    if (threadIdx.x == 0) bsum[blockIdx.x] = red[0];
}

// Phase B: single-block exclusive scan over nblk block sums (nblk <= 1024).
__global__ __launch_bounds__(1024) void scan_bsum_kernel(int* __restrict__ bsum, int nblk) {
    __shared__ int part[1024];
    int tid = threadIdx.x;
    int v = (tid < nblk) ? bsum[tid] : 0;
    part[tid] = v;
    __syncthreads();
    for (int off = 1; off < 1024; off <<= 1) {
        int t = (tid >= off) ? part[tid - off] : 0;
        __syncthreads();
        part[tid] += t;
        __syncthreads();
    }
    if (tid < nblk) bsum[tid] = part[tid] - v;   // exclusive
}

// Phase C: rowptr[i] = bsum[b] + block-exclusive-scan(tot); rowptr[N] = E.
__global__ __launch_bounds__(256) void rowptr_kernel(const int* __restrict__ totals,
                                                     const int* __restrict__ bsum,
                                                     int* __restrict__ rowptr, int N, int E) {
    __shared__ int part[256];
    int tid = threadIdx.x;
    int i = blockIdx.x * 256 + tid;
    int v = (i < N) ? totals[i] : 0;
    part[tid] = v;
    __syncthreads();
    for (int off = 1; off < 256; off <<= 1) {
        int t = (tid >= off) ? part[tid - off] : 0;
        __syncthreads();
        part[tid] += t;
        __syncthreads();
    }
    if (i < N) rowptr[i] = bsum[blockIdx.x] + part[tid] - v;
    if (i == 0) rowptr[N] = E;
}

// ---------------- CSR fill from partitioned pairs; per-edge base gathers; u16 csr -----------
__global__ __launch_bounds__(256) void fill_kernel(const u32* __restrict__ pairs,
                                                   const int* __restrict__ rof,
                                                   const int* __restrict__ rowptr,
                                                   const u16* __restrict__ pcol,
                                                   u16* __restrict__ csr,
                                                   int N, int cpb) {
    __shared__ alignas(16) int hist[RS];
    const int kc = blockIdx.x, r = blockIdx.y, tid = threadIdx.x;
    const int rbase = r << RSH;
    for (int j = tid; j < RS / 4; j += 256) ((int4*)hist)[j] = make_int4(0, 0, 0, 0);
    __syncthreads();
    for (int g = 0; g < GP; g++) {
        const int kp = kc * GP + g;
        const size_t base = (size_t)kp * cpb;
        const int s = rof[kp*16 + r], e = rof[kp*16 + r + 1];
        for (int i = s + tid; i < e; i += 256) {
            u32 p = pairs[base + i];
            int c = (int)(p & 0xFFFFu);
            int src = (int)(p >> 16);
            int loc = atomicAdd(&hist[c - rbase], 1);
            int pos = rowptr[c] + (int)pcol[(size_t)kc * N + c] + loc;
            csr[pos] = (u16)src;
        }
    }
}

// ---------------- W transpose+convert, ONCE (was: per-block LDS staging in gemm) -----------
// Wt[n*128+k] = bf16(W[k*128+n]).  Tiny (64KB read), runs in ~2us, shared by 782 gemm blocks.
__global__ __launch_bounds__(256) void wconv_kernel(const float* __restrict__ W1,
                                                    const float* __restrict__ W2,
                                                    u16* __restrict__ wt1,
                                                    u16* __restrict__ wt2) {
    int i = blockIdx.x * 256 + threadIdx.x;   // i = n*128 + k
    int n = i >> 7, k = i & 127;
    wt1[i] = f32_to_bf16(W1[k * 128 + n]);
    wt2[i] = f32_to_bf16(W2[k * 128 + n]);
}

// ---------------- dense transform: H' = dis .* (X @ W)  (f32 in, bf16 MFMA, bf16 out) --------
// B-fragments read straight from the pre-transposed global Wt (32KB, L1/L2-resident for all
// blocks) -> no LDS, no staging barrier, higher occupancy.
__global__ __launch_bounds__(256) void gemm_xw(const float* __restrict__ X,
                                               const u16* __restrict__ Wt,
                                               const float* __restrict__ dis,
                                               u16* __restrict__ H, int M) {
    const int tid = threadIdx.x;
    const int lane = tid & 63, wave = tid >> 6;
    const int quad = lane >> 4, r = lane & 15;
    int arow = blockIdx.x * 64 + wave * 16 + r;        // A-operand row (m = lane&15)
    if (arow >= M) arow = M - 1;
    const float* xrow = X + (size_t)arow * 128;

    float4v acc[8];
#pragma unroll
    for (int i = 0; i < 8; i++) acc[i] = (float4v)(0.0f);

#pragma unroll
    for (int kk = 0; kk < 4; kk++) {
        const int k0 = kk * 32 + quad * 8;             // a[j] = A[m][k0+j]
        float4 x0 = *(const float4*)(xrow + k0);
        float4 x1 = *(const float4*)(xrow + k0 + 4);
        short8 a;
        a[0] = (short)f32_to_bf16(x0.x); a[1] = (short)f32_to_bf16(x0.y);
        a[2] = (short)f32_to_bf16(x0.z); a[3] = (short)f32_to_bf16(x0.w);
        a[4] = (short)f32_to_bf16(x1.x); a[5] = (short)f32_to_bf16(x1.y);
        a[6] = (short)f32_to_bf16(x1.z); a[7] = (short)f32_to_bf16(x1.w);
#pragma unroll
        for (int nt = 0; nt < 8; nt++) {
            short8 b = *(const short8*)(Wt + (size_t)(nt * 16 + r) * 128 + k0);
            acc[nt] = __builtin_amdgcn_mfma_f32_16x16x32_bf16(a, b, acc[nt], 0, 0, 0);
        }
    }

    // C/D layout: col = lane&15 (=r), row-in-tile = quad*4 + reg
    const int orow0 = blockIdx.x * 64 + wave * 16 + quad * 4;
#pragma unroll
    for (int reg = 0; reg < 4; reg++) {
        int gr = orow0 + reg;
        if (gr < M) {
            float dscale = dis[gr];
            u16* hp = H + (size_t)gr * 128 + r;
#pragma unroll
            for (int nt = 0; nt < 8; nt++) hp[nt * 16] = f32_to_bf16(dscale * acc[nt][reg]);
        }
    }
}

// ---------------- aggregation: out[i] = dis[i]*(sum h'[src] + h'[i]) + b --------------------
// One wave per node. Lane-group g (=lane>>4) handles edges j%4==g; each lane loads 16B
// (8 channels) of the 256B row. R11: 16-edge batches keep FOUR dwordx4 gathers in flight
// (was 2 -- counters showed VALU 38% / HBM 45% / occ 68%: latency-bound, not a roofline);
// self-row + bias + dis hoisted before the loop; float2 packed accumulators (SLP->pk_add).
// All __shfl wave-uniform (R7 lesson: shfl from exec-masked lane is undefined).
__device__ inline void acc_add(float2* a, uint4 v) {
    a[0].x += bf16_lo(v.x); a[0].y += bf16_hi(v.x);
    a[1].x += bf16_lo(v.y); a[1].y += bf16_hi(v.y);
    a[2].x += bf16_lo(v.z); a[2].y += bf16_hi(v.z);
    a[3].x += bf16_lo(v.w); a[3].y += bf16_hi(v.w);
}

__global__ __launch_bounds__(256) void agg_kernel(const u16* __restrict__ h,
                                                  const float* __restrict__ dis,
                                                  const int* __restrict__ rowptr,
                                                  const u16* __restrict__ csr,
                                                  const float* __restrict__ bias,
                                                  float* __restrict__ out,
                                                  int N, int do_relu) {
    const int wave = threadIdx.x >> 6, lane = threadIdx.x & 63;
    const int node = blockIdx.x * 4 + wave;
    if (node >= N) return;
    const int grp = lane >> 4;        // edge phase 0..3
    const int sub = lane & 15;        // channels sub*8 .. sub*8+7

    int e = rowptr[node];
    const int end = rowptr[node + 1];

    // hoisted: self row, bias, dis (off the post-loop critical path)
    uint4 vs = *(const uint4*)(h + (size_t)node * 128 + sub * 8);
    float4 b0 = *(const float4*)(bias + sub * 8);
    float4 b1 = *(const float4*)(bias + sub * 8 + 4);
    const float di = dis[node];

    float2 acc[4];
#pragma unroll
    for (int i = 0; i < 4; i++) acc[i] = make_float2(0.0f, 0.0f);

    while (e < end) {
        const int nb = min(64, end - e);
        int s = (int)csr[min(e + lane, end - 1)];   // coalesced batch of up to 64 src ids
        int j0 = 0;
        for (; j0 + 16 <= nb; j0 += 16) {           // 4 independent 4-row gathers in flight
            int sa = __shfl(s, j0 + grp);
            int sb = __shfl(s, j0 + 4 + grp);
            int sc = __shfl(s, j0 + 8 + grp);
            int sd = __shfl(s, j0 + 12 + grp);
            uint4 va = *(const uint4*)(h + (size_t)sa * 128 + sub * 8);
            uint4 vb = *(const uint4*)(h + (size_t)sb * 128 + sub * 8);
            uint4 vc = *(const uint4*)(h + (size_t)sc * 128 + sub * 8);
            uint4 vd = *(const uint4*)(h + (size_t)sd * 128 + sub * 8);
            acc_add(acc, va); acc_add(acc, vb);
            acc_add(acc, vc); acc_add(acc, vd);
        }
        for (; j0 + 8 <= nb; j0 += 8) {             // 2 gathers in flight
            int ja = j0 + grp, jb = j0 + 4 + grp;
            int sa = __shfl(s, ja), sb = __shfl(s, jb);
            uint4 va = *(const uint4*)(h + (size_t)sa * 128 + sub * 8);
            uint4 vb = *(const uint4*)(h + (size_t)sb * 128 + sub * 8);
            acc_add(acc, va); acc_add(acc, vb);
        }
        for (; j0 < nb; j0 += 4) {
            int j = j0 + grp;                        // j <= 63 always
            int sj = __shfl(s, j);                   // UNIFORM: every lane executes this
            if (j < nb) {                            // divergence only around load+accum
                uint4 v = *(const uint4*)(h + (size_t)sj * 128 + sub * 8);
                acc_add(acc, v);
            }
        }
        e += nb;
    }

    // merge the 4 edge-phase groups (all cover the same channel set)
#pragma unroll
    for (int i = 0; i < 4; i++) {
        acc[i].x += __shfl_xor(acc[i].x, 16);
        acc[i].y += __shfl_xor(acc[i].y, 16);
        acc[i].x += __shfl_xor(acc[i].x, 32);
        acc[i].y += __shfl_xor(acc[i].y, 32);
    }

    if (grp == 0) {   // lanes 0-15 finalize + store the 512B f32 row
        float r0 = di * (acc[0].x + bf16_lo(vs.x)) + b0.x;
        float r1 = di * (acc[0].y + bf16_hi(vs.x)) + b0.y;
        float r2 = di * (acc[1].x + bf16_lo(vs.y)) + b0.z;
        float r3 = di * (acc[1].y + bf16_hi(vs.y)) + b0.w;
        float r4 = di * (acc[2].x + bf16_lo(vs.z)) + b1.x;
        float r5 = di * (acc[2].y + bf16_hi(vs.z)) + b1.y;
        float r6 = di * (acc[3].x + bf16_lo(vs.w)) + b1.z;
        float r7 = di * (acc[3].y + bf16_hi(vs.w)) + b1.w;
        if (do_relu) {
            r0 = fmaxf(r0, 0.0f); r1 = fmaxf(r1, 0.0f); r2 = fmaxf(r2, 0.0f); r3 = fmaxf(r3, 0.0f);
            r4 = fmaxf(r4, 0.0f); r5 = fmaxf(r5, 0.0f); r6 = fmaxf(r6, 0.0f); r7 = fmaxf(r7, 0.0f);
        }
        float* op = out + (size_t)node * 128 + sub * 8;
        *(float4*)op = make_float4(r0, r1, r2, r3);
        *(float4*)(op + 4) = make_float4(r4, r5, r6, r7);
    }
}

// ---------------- launch ----------------

extern "C" void kernel_launch(void* const* d_in, const int* in_sizes, int n_in,
                              void* d_out, int out_size, void* d_ws, size_t ws_size,
                              hipStream_t stream) {
    const float* x  = (const float*)d_in[0];   // [N,128] f32
    const int*   ei = (const int*)d_in[1];     // [2,E] int32
    const float* W1 = (const float*)d_in[2];   // [128,128] f32
    const float* b1 = (const float*)d_in[3];   // [128] f32
    const float* W2 = (const float*)d_in[4];
    const float* b2 = (const float*)d_in[5];
    float* out = (float*)d_out;                // [N,128] f32

    const int N = in_sizes[0] / 128;
    const int E = in_sizes[1] / 2;
    const int* er = ei;        // sources (gathered)
    const int* ec = ei + E;    // destinations (scattered)

    char* ws = (char*)d_ws;
    size_t off = 0;
    auto alloc = [&](size_t b) { size_t o = off; off += (b + 255) & ~(size_t)255; return o; };
    size_t o_tot  = alloc((size_t)N * 4);
    size_t o_rp   = alloc((size_t)(N + 1) * 4);
    size_t o_dis  = alloc((size_t)N * 4);
    size_t o_bsum = alloc((size_t)1024 * 4);
    size_t o_rof  = alloc((size_t)1024 * 16 * 4);
    size_t o_srof = alloc((size_t)1024 * 16 * 4);
    size_t o_csr  = alloc((size_t)E * 2);
    size_t o_h    = alloc((size_t)N * 128 * 2);
    size_t o_wt1  = alloc((size_t)128 * 128 * 2);
    size_t o_wt2  = alloc((size_t)128 * 128 * 2);
    size_t o_prs  = alloc((size_t)(E + 1024) * 4);
    size_t o_srcp = alloc((size_t)(E + 1024) * 2);

    size_t rem = (ws_size > off + 4096) ? (ws_size - off - 4096) : 0;
    long long nc = (long long)(rem / (3 * (size_t)N));
    if (nc > 128) nc = 128;
    if (nc < 16) nc = 16;
    nc &= ~15LL;                              // NC multiple of 16 (chunk_scan needs NC%16==0)
    const int NC = (int)nc, NCD = NC / 2;
    const int NCP = NC * GP;                 // partition chunks
    const int GPD = NCP / NCD;               // = 16

    size_t o_pcol = alloc((size_t)NC * N * 2);
    size_t o_pdeg = alloc((size_t)NCD * N * 2);

    int*   tot  = (int*)(ws + o_tot);
    int*   rp   = (int*)(ws + o_rp);
    float* dis  = (float*)(ws + o_dis);
    int*   bsum = (int*)(ws + o_bsum);
    int*   rof  = (int*)(ws + o_rof);
    int*   srof = (int*)(ws + o_srof);
    u16*   csr  = (u16*)(ws + o_csr);
    u16*   h    = (u16*)(ws + o_h);
    u16*   wt1  = (u16*)(ws + o_wt1);
    u16*   wt2  = (u16*)(ws + o_wt2);
    u32*   prs  = (u32*)(ws + o_prs);
    u16*   srcp = (u16*)(ws + o_srcp);
    u16*   pcol = (u16*)(ws + o_pcol);
    u16*   pdeg = (u16*)(ws + o_pdeg);

    const int NR = (N + RS - 1) / RS;        // 7 for N=50000 (must be <= 15)
    const int cpb  = (E + NCP - 1) / NCP;
    const int nblk = (N + 255) / 256;        // 196 (<= 1024 required)
    const int csblk = (int)(((size_t)N * 8 + 255) / 256);

    wconv_kernel<<<64, 256, 0, stream>>>(W1, W2, wt1, wt2);
    partition_kernel<<<NCP, 256, 0, stream>>>(er, ec, prs, srcp, rof, srof, E, cpb, NR);
    colhist_kernel<<<dim3(NC, NR), 256, 0, stream>>>(prs, rof, pcol, N, cpb);
    deghist_kernel<<<dim3(NCD, NR), 256, 0, stream>>>(srcp, srof, pdeg, N, cpb, GPD);
    chunk_scan_kernel<<<csblk, 256, 0, stream>>>(pcol, pdeg, tot, dis, N, NC, NCD);
    bsum_kernel<<<nblk, 256, 0, stream>>>(tot, bsum, N);
    scan_bsum_kernel<<<1, 1024, 0, stream>>>(bsum, nblk);
    rowptr_kernel<<<nblk, 256, 0, stream>>>(tot, bsum, rp, N, E);
    fill_kernel<<<dim3(NC, NR), 256, 0, stream>>>(prs, rof, rp, pcol, csr, N, cpb);

    // layer 1: h' = dis.*bf16(x@W1) ; d_out = relu(agg(h') + b1)
    gemm_xw<<<(N + 63) / 64, 256, 0, stream>>>(x, wt1, dis, h, N);
    agg_kernel<<<(N + 3) / 4, 256, 0, stream>>>(h, dis, rp, csr, b1, out, N, 1);

    // layer 2: h' = dis.*bf16(d_out@W2) ; d_out = agg(h') + b2
    gemm_xw<<<(N + 63) / 64, 256, 0, stream>>>(out, wt2, dis, h, N);
    agg_kernel<<<(N + 3) / 4, 256, 0, stream>>>(h, dis, rp, csr, b2, out, N, 0);
}

// Round 2
// 298.118 us; speedup vs baseline: 1.0346x; 1.0346x over previous
//
#include <hip/hip_runtime.h>

typedef unsigned short u16;
typedef unsigned int u32;
typedef __attribute__((ext_vector_type(8))) short short8;
typedef __attribute__((ext_vector_type(4))) float float4v;

#define LDS_S 136   // padded row stride (bf16 elems) for W tile in LDS (breaks 256B bank stride)
#define RS 8192     // node-range size (32KB LDS int counters)
#define RSH 13
#define GP 8        // partition chunks per col-chunk

__device__ inline float bf16_lo(u32 v) { return __uint_as_float(v << 16); }
__device__ inline float bf16_hi(u32 v) { return __uint_as_float(v & 0xFFFF0000u); }

__device__ inline u16 f32_to_bf16(float f) {
    u32 u = __float_as_uint(f);
    u32 r = u + 0x7FFFu + ((u >> 16) & 1u);   // round-to-nearest-even
    return (u16)(r >> 16);
}

// ---------------- P0: partition edges by col-range (pairs) and src-range (srcp) -------------
__global__ __launch_bounds__(256) void partition_kernel(const int* __restrict__ er,
                                                        const int* __restrict__ ec,
                                                        u32* __restrict__ pairs,
                                                        u16* __restrict__ srcp,
                                                        int* __restrict__ rof,
                                                        int* __restrict__ srof,
                                                        int E, int cpb, int NR) {
    __shared__ int cnt[16], scnt[16];
    const int k = blockIdx.x, tid = threadIdx.x;
    const int e0 = k * cpb, e1 = min(e0 + cpb, E);
    if (tid < 16) { cnt[tid] = 0; scnt[tid] = 0; }
    __syncthreads();
    for (int e = e0 + tid; e < e1; e += 256) {
        atomicAdd(&cnt[ec[e] >> RSH], 1);
        atomicAdd(&scnt[er[e] >> RSH], 1);
    }
    __syncthreads();
    if (tid == 0) {
        int run = 0;
        for (int r = 0; r < NR; r++) { int c = cnt[r]; rof[k*16 + r] = run; cnt[r] = run; run += c; }
        rof[k*16 + NR] = run;
        run = 0;
        for (int r = 0; r < NR; r++) { int c = scnt[r]; srof[k*16 + r] = run; scnt[r] = run; run += c; }
        srof[k*16 + NR] = run;
    }
    __syncthreads();
    const size_t base = (size_t)k * cpb;
    for (int e = e0 + tid; e < e1; e += 256) {
        int s = er[e], c = ec[e];
        int slot = atomicAdd(&cnt[c >> RSH], 1);
        pairs[base + slot] = ((u32)s << 16) | (u32)c;
        int slot2 = atomicAdd(&scnt[s >> RSH], 1);
        srcp[base + slot2] = (u16)s;
    }
}

// ---------------- col histogram over partitioned pairs -> pcol u16 --------------------------
__global__ __launch_bounds__(256) void colhist_kernel(const u32* __restrict__ pairs,
                                                      const int* __restrict__ rof,
                                                      u16* __restrict__ pcol,
                                                      int N, int cpb) {
    __shared__ alignas(16) int hist[RS];
    const int kc = blockIdx.x, r = blockIdx.y, tid = threadIdx.x;
    const int rbase = r << RSH;
    const int rcount = min(RS, N - rbase);
    for (int j = tid; j < RS / 4; j += 256) ((int4*)hist)[j] = make_int4(0, 0, 0, 0);
    __syncthreads();
    for (int g = 0; g < GP; g++) {
        const int kp = kc * GP + g;
        const size_t base = (size_t)kp * cpb;
        const int s = rof[kp*16 + r], e = rof[kp*16 + r + 1];
        for (int i = s + tid; i < e; i += 256) {
            u32 p = pairs[base + i];
            atomicAdd(&hist[(int)(p & 0xFFFFu) - rbase], 1);
        }
    }
    __syncthreads();
    for (int j = tid; j < rcount; j += 256)
        pcol[(size_t)kc * N + rbase + j] = (u16)hist[j];
}

// ---------------- deg histogram over partitioned srcs -> pdeg u16 ---------------------------
__global__ __launch_bounds__(256) void deghist_kernel(const u16* __restrict__ srcp,
                                                      const int* __restrict__ srof,
                                                      u16* __restrict__ pdeg,
                                                      int N, int cpb, int GPD) {
    __shared__ alignas(16) int hist[RS];
    const int kd = blockIdx.x, r = blockIdx.y, tid = threadIdx.x;
    const int rbase = r << RSH;
    const int rcount = min(RS, N - rbase);
    for (int j = tid; j < RS / 4; j += 256) ((int4*)hist)[j] = make_int4(0, 0, 0, 0);
    __syncthreads();
    for (int g = 0; g < GPD; g++) {
        const int kp = kd * GPD + g;
        const size_t base = (size_t)kp * cpb;
        const int s = srof[kp*16 + r], e = srof[kp*16 + r + 1];
        for (int i = s + tid; i < e; i += 256)
            atomicAdd(&hist[(int)srcp[base + i] - rbase], 1);
    }
    __syncthreads();
    for (int j = tid; j < rcount; j += 256)
        pdeg[(size_t)kd * N + rbase + j] = (u16)hist[j];
}

// ---------------- chunk scan: 8 threads/node, register-batched loads + shfl prefix ----------
__global__ __launch_bounds__(256) void chunk_scan_kernel(u16* __restrict__ pcol,
                                                         const u16* __restrict__ pdeg,
                                                         int* __restrict__ totals,
                                                         float* __restrict__ dis,
                                                         int N, int NC, int NCD) {
    const int gid = blockIdx.x * 256 + threadIdx.x;
    const int node = gid >> 3;
    const int t = threadIdx.x & 7;
    if (node >= N) return;
    const int per = NC >> 3;     // <= 16 (NC multiple of 16)
    const int k0 = t * per;
    int vals[16];
    int sum = 0;
#pragma unroll
    for (int j = 0; j < 16; j++) {      // independent guarded loads -> one latency round trip
        int v = 0;
        if (j < per) v = pcol[(size_t)(k0 + j) * N + node];
        vals[j] = v;
        sum += v;
    }
    int inc = sum;                       // inclusive scan across the node's 8 lanes
#pragma unroll
    for (int d = 1; d < 8; d <<= 1) {
        int v = __shfl_up(inc, d, 8);    // wave-uniform; sources within same 8-group
        if (t >= d) inc += v;
    }
    int run = inc - sum;                 // exclusive base for this thread's chunk span
#pragma unroll
    for (int j = 0; j < 16; j++) {
        if (j < per) {
            pcol[(size_t)(k0 + j) * N + node] = (u16)run;
            run += vals[j];
        }
    }
    if (t == 7) totals[node] = inc;      // lane 7's inclusive = node total

    const int perd = NCD >> 3;           // <= 8 (NCD multiple of 8)
    int s = 0;
#pragma unroll
    for (int j = 0; j < 8; j++) {
        if (j < perd) s += pdeg[(size_t)(t * perd + j) * N + node];
    }
    s += __shfl_xor(s, 1);
    s += __shfl_xor(s, 2);
    s += __shfl_xor(s, 4);
    if (t == 0) dis[node] = rsqrtf((float)(s + 1));  // +1 self loop; always > 0
}

// Phase A': per-256-node block sums of totals.
__global__ __launch_bounds__(256) void bsum_kernel(const int* __restrict__ totals,
                                                   int* __restrict__ bsum, int N) {
    __shared__ int red[256];
    int i = blockIdx.x * 256 + threadIdx.x;
    red[threadIdx.x] = (i < N) ? totals[i] : 0;
    __syncthreads();
#pragma unroll
    for (int off = 128; off > 0; off >>= 1) {
        if (threadIdx.x < off) red[threadIdx.x] += red[threadIdx.x + off];
        __syncthreads();
    }
    if (threadIdx.x == 0) bsum[blockIdx.x] = red[0];
}

// Phase B: single-block exclusive scan over nblk block sums (nblk <= 1024).
__global__ __launch_bounds__(1024) void scan_bsum_kernel(int* __restrict__ bsum, int nblk) {
    __shared__ int part[1024];
    int tid = threadIdx.x;
    int v = (tid < nblk) ? bsum[tid] : 0;
    part[tid] = v;
    __syncthreads();
    for (int off = 1; off < 1024; off <<= 1) {
        int t = (tid >= off) ? part[tid - off] : 0;
        __syncthreads();
        part[tid] += t;
        __syncthreads();
    }
    if (tid < nblk) bsum[tid] = part[tid] - v;   // exclusive
}

// Phase C: rowptr[i] = bsum[b] + block-exclusive-scan(tot); rowptr[N] = E.
__global__ __launch_bounds__(256) void rowptr_kernel(const int* __restrict__ totals,
                                                     const int* __restrict__ bsum,
                                                     int* __restrict__ rowptr, int N, int E) {
    __shared__ int part[256];
    int tid = threadIdx.x;
    int i = blockIdx.x * 256 + tid;
    int v = (i < N) ? totals[i] : 0;
    part[tid] = v;
    __syncthreads();
    for (int off = 1; off < 256; off <<= 1) {
        int t = (tid >= off) ? part[tid - off] : 0;
        __syncthreads();
        part[tid] += t;
        __syncthreads();
    }
    if (i < N) rowptr[i] = bsum[blockIdx.x] + part[tid] - v;
    if (i == 0) rowptr[N] = E;
}

// ---------------- CSR fill from partitioned pairs; per-edge base gathers; u16 csr -----------
__global__ __launch_bounds__(256) void fill_kernel(const u32* __restrict__ pairs,
                                                   const int* __restrict__ rof,
                                                   const int* __restrict__ rowptr,
                                                   const u16* __restrict__ pcol,
                                                   u16* __restrict__ csr,
                                                   int N, int cpb) {
    __shared__ alignas(16) int hist[RS];
    const int kc = blockIdx.x, r = blockIdx.y, tid = threadIdx.x;
    const int rbase = r << RSH;
    for (int j = tid; j < RS / 4; j += 256) ((int4*)hist)[j] = make_int4(0, 0, 0, 0);
    __syncthreads();
    for (int g = 0; g < GP; g++) {
        const int kp = kc * GP + g;
        const size_t base = (size_t)kp * cpb;
        const int s = rof[kp*16 + r], e = rof[kp*16 + r + 1];
        for (int i = s + tid; i < e; i += 256) {
            u32 p = pairs[base + i];
            int c = (int)(p & 0xFFFFu);
            int src = (int)(p >> 16);
            int loc = atomicAdd(&hist[c - rbase], 1);
            int pos = rowptr[c] + (int)pcol[(size_t)kc * N + c] + loc;
            csr[pos] = (u16)src;
        }
    }
}

// ---------------- W transpose+convert, ONCE ------------------------------------------------
// Wt[n*128+k] = bf16(W[k][n]). R11 lesson: reading B-fragments from global inside the MFMA
// loop regressed gemm (lost LDS broadcast + per-wave VMEM). Keep wconv (kills the 16K scalar
// f32->bf16 per block) but stage the pre-converted Wt into LDS with 8 dwordx4 copies.
__global__ __launch_bounds__(256) void wconv_kernel(const float* __restrict__ W1,
                                                    const float* __restrict__ W2,
                                                    u16* __restrict__ wt1,
                                                    u16* __restrict__ wt2) {
    int i = blockIdx.x * 256 + threadIdx.x;   // i = n*128 + k
    int n = i >> 7, k = i & 127;
    wt1[i] = f32_to_bf16(W1[k * 128 + n]);
    wt2[i] = f32_to_bf16(W2[k * 128 + n]);
}

// ---------------- dense transform: H' = dis .* (X @ W)  (f32 in, bf16 MFMA, bf16 out) --------
__global__ __launch_bounds__(256) void gemm_xw(const float* __restrict__ X,
                                               const u16* __restrict__ Wt,  // [128][128] bf16, transposed
                                               const float* __restrict__ dis,
                                               u16* __restrict__ H, int M) {
    __shared__ u16 Ws[128 * LDS_S];
    const int tid = threadIdx.x;
    // stage 32KB pre-converted Wt: 2048 16B chunks, 8 per thread, no ALU conversion
    for (int c = tid; c < 2048; c += 256) {
        int row = c >> 4, ch = c & 15;
        *(uint4*)(&Ws[row * LDS_S + ch * 8]) = *(const uint4*)(Wt + row * 128 + ch * 8);
    }
    __syncthreads();

    const int lane = tid & 63, wave = tid >> 6;
    const int quad = lane >> 4, r = lane & 15;
    int arow = blockIdx.x * 64 + wave * 16 + r;        // A-operand row (m = lane&15)
    if (arow >= M) arow = M - 1;
    const float* xrow = X + (size_t)arow * 128;

    float4v acc[8];
#pragma unroll
    for (int i = 0; i < 8; i++) acc[i] = (float4v)(0.0f);

#pragma unroll
    for (int kk = 0; kk < 4; kk++) {
        const int k0 = kk * 32 + quad * 8;             // a[j] = A[m][k0+j]
        float4 x0 = *(const float4*)(xrow + k0);
        float4 x1 = *(const float4*)(xrow + k0 + 4);
        short8 a;
        a[0] = (short)f32_to_bf16(x0.x); a[1] = (short)f32_to_bf16(x0.y);
        a[2] = (short)f32_to_bf16(x0.z); a[3] = (short)f32_to_bf16(x0.w);
        a[4] = (short)f32_to_bf16(x1.x); a[5] = (short)f32_to_bf16(x1.y);
        a[6] = (short)f32_to_bf16(x1.z); a[7] = (short)f32_to_bf16(x1.w);
#pragma unroll
        for (int nt = 0; nt < 8; nt++) {
            short8 b = *(const short8*)(&Ws[(nt * 16 + r) * LDS_S + k0]);
            acc[nt] = __builtin_amdgcn_mfma_f32_16x16x32_bf16(a, b, acc[nt], 0, 0, 0);
        }
    }

    // C/D layout: col = lane&15 (=r), row-in-tile = quad*4 + reg
    const int orow0 = blockIdx.x * 64 + wave * 16 + quad * 4;
#pragma unroll
    for (int reg = 0; reg < 4; reg++) {
        int gr = orow0 + reg;
        if (gr < M) {
            float dscale = dis[gr];
            u16* hp = H + (size_t)gr * 128 + r;
#pragma unroll
            for (int nt = 0; nt < 8; nt++) hp[nt * 16] = f32_to_bf16(dscale * acc[nt][reg]);
        }
    }
}

// ---------------- aggregation: out[i] = dis[i]*(sum h'[src] + h'[i]) + b --------------------
// R12: TWO nodes per wave, chains interleaved. R11 counters (45% HBM, 37% VALU, 0 MFMA,
// FETCH fixed at 151MB) => latency/MLP-bound: one node/wave = serial rowptr->csr->gather
// chain, ~4.6KB in flight per CU vs ~12KB needed for 6.3TB/s. Two interleaved chains double
// in-flight loads (8 gathers in the bulk loop) and amortize rowptr/csr latency; rowptr for
// the pair is one contiguous 3-int read (e1 == end0). Output rows store in parallel from
// lane-groups 0 and 1. All __shfl wave-uniform (R7 lesson).
__device__ inline void acc_add(float2* a, uint4 v) {
    a[0].x += bf16_lo(v.x); a[0].y += bf16_hi(v.x);
    a[1].x += bf16_lo(v.y); a[1].y += bf16_hi(v.y);
    a[2].x += bf16_lo(v.z); a[2].y += bf16_hi(v.z);
    a[3].x += bf16_lo(v.w); a[3].y += bf16_hi(v.w);
}

__global__ __launch_bounds__(256) void agg_kernel(const u16* __restrict__ h,
                                                  const float* __restrict__ dis,
                                                  const int* __restrict__ rowptr,
                                                  const u16* __restrict__ csr,
                                                  const float* __restrict__ bias,
                                                  float* __restrict__ out,
                                                  int N, int do_relu) {
    const int wave = threadIdx.x >> 6, lane = threadIdx.x & 63;
    const int n0 = (blockIdx.x * 4 + wave) * 2;
    if (n0 >= N) return;
    const int n1 = n0 + 1;
    const int has1 = (n1 < N);
    const int grp = lane >> 4;        // edge phase 0..3
    const int sub = lane & 15;        // channels sub*8 .. sub*8+7

    // one contiguous rowptr read covers both nodes: [e0, end0(=e1), end1]
    int e0 = rowptr[n0];
    int end0 = rowptr[n0 + 1];
    int e1 = end0;
    int end1 = has1 ? rowptr[n0 + 2] : end0;

    // hoisted: self rows, bias, dis
    uint4 vs0 = *(const uint4*)(h + (size_t)n0 * 128 + sub * 8);
    uint4 vs1 = vs0;
    if (has1) vs1 = *(const uint4*)(h + (size_t)n1 * 128 + sub * 8);
    float4 bb0 = *(const float4*)(bias + sub * 8);
    float4 bb1 = *(const float4*)(bias + sub * 8 + 4);
    const float di0 = dis[n0];
    const float di1 = has1 ? dis[n1] : 0.0f;

    float2 acc0[4], acc1[4];
#pragma unroll
    for (int i = 0; i < 4; i++) { acc0[i] = make_float2(0.f, 0.f); acc1[i] = make_float2(0.f, 0.f); }

    while (e0 < end0 || e1 < end1) {
        int nb0 = 0, nb1 = 0, s0 = 0, s1 = 0;
        if (e0 < end0) { nb0 = min(64, end0 - e0); s0 = (int)csr[min(e0 + lane, end0 - 1)]; }
        if (e1 < end1) { nb1 = min(64, end1 - e1); s1 = (int)csr[min(e1 + lane, end1 - 1)]; }
        int i0 = 0, i1 = 0;

        // joint bulk: 16 edges per node -> 8 independent dwordx4 gathers in flight
        while (i0 + 16 <= nb0 && i1 + 16 <= nb1) {
            int a0 = __shfl(s0, i0 + grp),      a1 = __shfl(s0, i0 + 4 + grp);
            int a2 = __shfl(s0, i0 + 8 + grp),  a3 = __shfl(s0, i0 + 12 + grp);
            int c0 = __shfl(s1, i1 + grp),      c1 = __shfl(s1, i1 + 4 + grp);
            int c2 = __shfl(s1, i1 + 8 + grp),  c3 = __shfl(s1, i1 + 12 + grp);
            uint4 va = *(const uint4*)(h + (size_t)a0 * 128 + sub * 8);
            uint4 vb = *(const uint4*)(h + (size_t)a1 * 128 + sub * 8);
            uint4 vc = *(const uint4*)(h + (size_t)a2 * 128 + sub * 8);
            uint4 vd = *(const uint4*)(h + (size_t)a3 * 128 + sub * 8);
            uint4 ve = *(const uint4*)(h + (size_t)c0 * 128 + sub * 8);
            uint4 vf = *(const uint4*)(h + (size_t)c1 * 128 + sub * 8);
            uint4 vg = *(const uint4*)(h + (size_t)c2 * 128 + sub * 8);
            uint4 vh = *(const uint4*)(h + (size_t)c3 * 128 + sub * 8);
            acc_add(acc0, va); acc_add(acc0, vb); acc_add(acc0, vc); acc_add(acc0, vd);
            acc_add(acc1, ve); acc_add(acc1, vf); acc_add(acc1, vg); acc_add(acc1, vh);
            i0 += 16; i1 += 16;
        }
        // leftover bulk, single node (4 gathers in flight)
        while (i0 + 16 <= nb0) {
            int a0 = __shfl(s0, i0 + grp),     a1 = __shfl(s0, i0 + 4 + grp);
            int a2 = __shfl(s0, i0 + 8 + grp), a3 = __shfl(s0, i0 + 12 + grp);
            uint4 va = *(const uint4*)(h + (size_t)a0 * 128 + sub * 8);
            uint4 vb = *(const uint4*)(h + (size_t)a1 * 128 + sub * 8);
            uint4 vc = *(const uint4*)(h + (size_t)a2 * 128 + sub * 8);
            uint4 vd = *(const uint4*)(h + (size_t)a3 * 128 + sub * 8);
            acc_add(acc0, va); acc_add(acc0, vb); acc_add(acc0, vc); acc_add(acc0, vd);
            i0 += 16;
        }
        while (i1 + 16 <= nb1) {
            int c0 = __shfl(s1, i1 + grp),     c1 = __shfl(s1, i1 + 4 + grp);
            int c2 = __shfl(s1, i1 + 8 + grp), c3 = __shfl(s1, i1 + 12 + grp);
            uint4 ve = *(const uint4*)(h + (size_t)c0 * 128 + sub * 8);
            uint4 vf = *(const uint4*)(h + (size_t)c1 * 128 + sub * 8);
            uint4 vg = *(const uint4*)(h + (size_t)c2 * 128 + sub * 8);
            uint4 vh = *(const uint4*)(h + (size_t)c3 * 128 + sub * 8);
            acc_add(acc1, ve); acc_add(acc1, vf); acc_add(acc1, vg); acc_add(acc1, vh);
            i1 += 16;
        }
        // 8-edge chunks, single node (2 gathers in flight)
        while (i0 + 8 <= nb0) {
            int a0 = __shfl(s0, i0 + grp), a1 = __shfl(s0, i0 + 4 + grp);
            uint4 va = *(const uint4*)(h + (size_t)a0 * 128 + sub * 8);
            uint4 vb = *(const uint4*)(h + (size_t)a1 * 128 + sub * 8);
            acc_add(acc0, va); acc_add(acc0, vb);
            i0 += 8;
        }
        while (i1 + 8 <= nb1) {
            int c0 = __shfl(s1, i1 + grp), c1 = __shfl(s1, i1 + 4 + grp);
            uint4 ve = *(const uint4*)(h + (size_t)c0 * 128 + sub * 8);
            uint4 vf = *(const uint4*)(h + (size_t)c1 * 128 + sub * 8);
            acc_add(acc1, ve); acc_add(acc1, vf);
            i1 += 8;
        }
        // guarded 4-edge tails (i stays a multiple of 4 -> shfl index <= 63)
        for (; i0 < nb0; i0 += 4) {
            int j = i0 + grp;
            int sj = __shfl(s0, j);          // UNIFORM: every lane executes this
            if (j < nb0) {
                uint4 v = *(const uint4*)(h + (size_t)sj * 128 + sub * 8);
                acc_add(acc0, v);
            }
        }
        for (; i1 < nb1; i1 += 4) {
            int j = i1 + grp;
            int sj = __shfl(s1, j);
            if (j < nb1) {
                uint4 v = *(const uint4*)(h + (size_t)sj * 128 + sub * 8);
                acc_add(acc1, v);
            }
        }
        e0 += nb0; e1 += nb1;
    }

    // merge the 4 edge-phase groups (all cover the same channel set)
#pragma unroll
    for (int i = 0; i < 4; i++) {
        acc0[i].x += __shfl_xor(acc0[i].x, 16);
        acc0[i].y += __shfl_xor(acc0[i].y, 16);
        acc0[i].x += __shfl_xor(acc0[i].x, 32);
        acc0[i].y += __shfl_xor(acc0[i].y, 32);
        acc1[i].x += __shfl_xor(acc1[i].x, 16);
        acc1[i].y += __shfl_xor(acc1[i].y, 16);
        acc1[i].x += __shfl_xor(acc1[i].x, 32);
        acc1[i].y += __shfl_xor(acc1[i].y, 32);
    }

    // grp 0 stores node0, grp 1 stores node1 (parallel 512B f32 row stores)
    if (grp == 0 || (grp == 1 && has1)) {
        const int     node = (grp == 0) ? n0 : n1;
        const float   di   = (grp == 0) ? di0 : di1;
        const uint4   vs   = (grp == 0) ? vs0 : vs1;
        const float2* ac   = (grp == 0) ? acc0 : acc1;
        float r0 = di * (ac[0].x + bf16_lo(vs.x)) + bb0.x;
        float r1 = di * (ac[0].y + bf16_hi(vs.x)) + bb0.y;
        float r2 = di * (ac[1].x + bf16_lo(vs.y)) + bb0.z;
        float r3 = di * (ac[1].y + bf16_hi(vs.y)) + bb0.w;
        float r4 = di * (ac[2].x + bf16_lo(vs.z)) + bb1.x;
        float r5 = di * (ac[2].y + bf16_hi(vs.z)) + bb1.y;
        float r6 = di * (ac[3].x + bf16_lo(vs.w)) + bb1.z;
        float r7 = di * (ac[3].y + bf16_hi(vs.w)) + bb1.w;
        if (do_relu) {
            r0 = fmaxf(r0, 0.0f); r1 = fmaxf(r1, 0.0f); r2 = fmaxf(r2, 0.0f); r3 = fmaxf(r3, 0.0f);
            r4 = fmaxf(r4, 0.0f); r5 = fmaxf(r5, 0.0f); r6 = fmaxf(r6, 0.0f); r7 = fmaxf(r7, 0.0f);
        }
        float* op = out + (size_t)node * 128 + sub * 8;
        *(float4*)op = make_float4(r0, r1, r2, r3);
        *(float4*)(op + 4) = make_float4(r4, r5, r6, r7);
    }
}

// ---------------- launch ----------------

extern "C" void kernel_launch(void* const* d_in, const int* in_sizes, int n_in,
                              void* d_out, int out_size, void* d_ws, size_t ws_size,
                              hipStream_t stream) {
    const float* x  = (const float*)d_in[0];   // [N,128] f32
    const int*   ei = (const int*)d_in[1];     // [2,E] int32
    const float* W1 = (const float*)d_in[2];   // [128,128] f32
    const float* b1 = (const float*)d_in[3];   // [128] f32
    const float* W2 = (const float*)d_in[4];
    const float* b2 = (const float*)d_in[5];
    float* out = (float*)d_out;                // [N,128] f32

    const int N = in_sizes[0] / 128;
    const int E = in_sizes[1] / 2;
    const int* er = ei;        // sources (gathered)
    const int* ec = ei + E;    // destinations (scattered)

    char* ws = (char*)d_ws;
    size_t off = 0;
    auto alloc = [&](size_t b) { size_t o = off; off += (b + 255) & ~(size_t)255; return o; };
    size_t o_tot  = alloc((size_t)N * 4);
    size_t o_rp   = alloc((size_t)(N + 1) * 4);
    size_t o_dis  = alloc((size_t)N * 4);
    size_t o_bsum = alloc((size_t)1024 * 4);
    size_t o_rof  = alloc((size_t)1024 * 16 * 4);
    size_t o_srof = alloc((size_t)1024 * 16 * 4);
    size_t o_csr  = alloc((size_t)E * 2);
    size_t o_h    = alloc((size_t)N * 128 * 2);
    size_t o_wt1  = alloc((size_t)128 * 128 * 2);
    size_t o_wt2  = alloc((size_t)128 * 128 * 2);
    size_t o_prs  = alloc((size_t)(E + 1024) * 4);
    size_t o_srcp = alloc((size_t)(E + 1024) * 2);

    size_t rem = (ws_size > off + 4096) ? (ws_size - off - 4096) : 0;
    long long nc = (long long)(rem / (3 * (size_t)N));
    if (nc > 128) nc = 128;
    if (nc < 16) nc = 16;
    nc &= ~15LL;                              // NC multiple of 16 (chunk_scan needs NC%16==0)
    const int NC = (int)nc, NCD = NC / 2;
    const int NCP = NC * GP;                 // partition chunks
    const int GPD = NCP / NCD;               // = 16

    size_t o_pcol = alloc((size_t)NC * N * 2);
    size_t o_pdeg = alloc((size_t)NCD * N * 2);

    int*   tot  = (int*)(ws + o_tot);
    int*   rp   = (int*)(ws + o_rp);
    float* dis  = (float*)(ws + o_dis);
    int*   bsum = (int*)(ws + o_bsum);
    int*   rof  = (int*)(ws + o_rof);
    int*   srof = (int*)(ws + o_srof);
    u16*   csr  = (u16*)(ws + o_csr);
    u16*   h    = (u16*)(ws + o_h);
    u16*   wt1  = (u16*)(ws + o_wt1);
    u16*   wt2  = (u16*)(ws + o_wt2);
    u32*   prs  = (u32*)(ws + o_prs);
    u16*   srcp = (u16*)(ws + o_srcp);
    u16*   pcol = (u16*)(ws + o_pcol);
    u16*   pdeg = (u16*)(ws + o_pdeg);

    const int NR = (N + RS - 1) / RS;        // 7 for N=50000 (must be <= 15)
    const int cpb  = (E + NCP - 1) / NCP;
    const int nblk = (N + 255) / 256;        // 196 (<= 1024 required)
    const int csblk = (int)(((size_t)N * 8 + 255) / 256);

    wconv_kernel<<<64, 256, 0, stream>>>(W1, W2, wt1, wt2);
    partition_kernel<<<NCP, 256, 0, stream>>>(er, ec, prs, srcp, rof, srof, E, cpb, NR);
    colhist_kernel<<<dim3(NC, NR), 256, 0, stream>>>(prs, rof, pcol, N, cpb);
    deghist_kernel<<<dim3(NCD, NR), 256, 0, stream>>>(srcp, srof, pdeg, N, cpb, GPD);
    chunk_scan_kernel<<<csblk, 256, 0, stream>>>(pcol, pdeg, tot, dis, N, NC, NCD);
    bsum_kernel<<<nblk, 256, 0, stream>>>(tot, bsum, N);
    scan_bsum_kernel<<<1, 1024, 0, stream>>>(bsum, nblk);
    rowptr_kernel<<<nblk, 256, 0, stream>>>(tot, bsum, rp, N, E);
    fill_kernel<<<dim3(NC, NR), 256, 0, stream>>>(prs, rof, rp, pcol, csr, N, cpb);

    // layer 1: h' = dis.*bf16(x@W1) ; d_out = relu(agg(h') + b1)
    gemm_xw<<<(N + 63) / 64, 256, 0, stream>>>(x, wt1, dis, h, N);
    agg_kernel<<<(N + 7) / 8, 256, 0, stream>>>(h, dis, rp, csr, b1, out, N, 1);

    // layer 2: h' = dis.*bf16(d_out@W2) ; d_out = agg(h') + b2
    gemm_xw<<<(N + 63) / 64, 256, 0, stream>>>(out, wt2, dis, h, N);
    agg_kernel<<<(N + 7) / 8, 256, 0, stream>>>(h, dis, rp, csr, b2, out, N, 0);
}

// Round 4
// 279.946 us; speedup vs baseline: 1.1017x; 1.0649x over previous
//
#include <hip/hip_runtime.h>

typedef unsigned short u16;
typedef unsigned int u32;
typedef __attribute__((ext_vector_type(8))) short short8;
typedef __attribute__((ext_vector_type(4))) float float4v;

#define LDS_S 136   // padded row stride (bf16 elems) for W tile in LDS (breaks 256B bank stride)
#define RS 8192     // node-range size (32KB LDS int counters)
#define RSH 13
#define GP 8        // partition chunks per col-chunk

__device__ inline float bf16_lo(u32 v) { return __uint_as_float(v << 16); }
__device__ inline float bf16_hi(u32 v) { return __uint_as_float(v & 0xFFFF0000u); }

__device__ inline u16 f32_to_bf16(float f) {
    u32 u = __float_as_uint(f);
    u32 r = u + 0x7FFFu + ((u >> 16) & 1u);   // round-to-nearest-even
    return (u16)(r >> 16);
}

// ---------------- P0: partition edges by col-range (pairs) and src-range (srcp) -------------
__global__ __launch_bounds__(256) void partition_kernel(const int* __restrict__ er,
                                                        const int* __restrict__ ec,
                                                        u32* __restrict__ pairs,
                                                        u16* __restrict__ srcp,
                                                        int* __restrict__ rof,
                                                        int* __restrict__ srof,
                                                        int E, int cpb, int NR) {
    __shared__ int cnt[16], scnt[16];
    const int k = blockIdx.x, tid = threadIdx.x;
    const int e0 = k * cpb, e1 = min(e0 + cpb, E);
    if (tid < 16) { cnt[tid] = 0; scnt[tid] = 0; }
    __syncthreads();
    for (int e = e0 + tid; e < e1; e += 256) {
        atomicAdd(&cnt[ec[e] >> RSH], 1);
        atomicAdd(&scnt[er[e] >> RSH], 1);
    }
    __syncthreads();
    if (tid == 0) {
        int run = 0;
        for (int r = 0; r < NR; r++) { int c = cnt[r]; rof[k*16 + r] = run; cnt[r] = run; run += c; }
        rof[k*16 + NR] = run;
        run = 0;
        for (int r = 0; r < NR; r++) { int c = scnt[r]; srof[k*16 + r] = run; scnt[r] = run; run += c; }
        srof[k*16 + NR] = run;
    }
    __syncthreads();
    const size_t base = (size_t)k * cpb;
    for (int e = e0 + tid; e < e1; e += 256) {
        int s = er[e], c = ec[e];
        int slot = atomicAdd(&cnt[c >> RSH], 1);
        pairs[base + slot] = ((u32)s << 16) | (u32)c;
        int slot2 = atomicAdd(&scnt[s >> RSH], 1);
        srcp[base + slot2] = (u16)s;
    }
}

// ---------------- col histogram over partitioned pairs -> pcol u16 --------------------------
__global__ __launch_bounds__(256) void colhist_kernel(const u32* __restrict__ pairs,
                                                      const int* __restrict__ rof,
                                                      u16* __restrict__ pcol,
                                                      int N, int cpb) {
    __shared__ alignas(16) int hist[RS];
    const int kc = blockIdx.x, r = blockIdx.y, tid = threadIdx.x;
    const int rbase = r << RSH;
    const int rcount = min(RS, N - rbase);
    for (int j = tid; j < RS / 4; j += 256) ((int4*)hist)[j] = make_int4(0, 0, 0, 0);
    __syncthreads();
    for (int g = 0; g < GP; g++) {
        const int kp = kc * GP + g;
        const size_t base = (size_t)kp * cpb;
        const int s = rof[kp*16 + r], e = rof[kp*16 + r + 1];
        for (int i = s + tid; i < e; i += 256) {
            u32 p = pairs[base + i];
            atomicAdd(&hist[(int)(p & 0xFFFFu) - rbase], 1);
        }
    }
    __syncthreads();
    for (int j = tid; j < rcount; j += 256)
        pcol[(size_t)kc * N + rbase + j] = (u16)hist[j];
}

// ---------------- deg histogram over partitioned srcs -> pdeg u16 ---------------------------
__global__ __launch_bounds__(256) void deghist_kernel(const u16* __restrict__ srcp,
                                                      const int* __restrict__ srof,
                                                      u16* __restrict__ pdeg,
                                                      int N, int cpb, int GPD) {
    __shared__ alignas(16) int hist[RS];
    const int kd = blockIdx.x, r = blockIdx.y, tid = threadIdx.x;
    const int rbase = r << RSH;
    const int rcount = min(RS, N - rbase);
    for (int j = tid; j < RS / 4; j += 256) ((int4*)hist)[j] = make_int4(0, 0, 0, 0);
    __syncthreads();
    for (int g = 0; g < GPD; g++) {
        const int kp = kd * GPD + g;
        const size_t base = (size_t)kp * cpb;
        const int s = srof[kp*16 + r], e = srof[kp*16 + r + 1];
        for (int i = s + tid; i < e; i += 256)
            atomicAdd(&hist[(int)srcp[base + i] - rbase], 1);
    }
    __syncthreads();
    for (int j = tid; j < rcount; j += 256)
        pdeg[(size_t)kd * N + rbase + j] = (u16)hist[j];
}

// ---------------- chunk scan: 8 threads/node, register-batched loads + shfl prefix ----------
__global__ __launch_bounds__(256) void chunk_scan_kernel(u16* __restrict__ pcol,
                                                         const u16* __restrict__ pdeg,
                                                         int* __restrict__ totals,
                                                         float* __restrict__ dis,
                                                         int N, int NC, int NCD) {
    const int gid = blockIdx.x * 256 + threadIdx.x;
    const int node = gid >> 3;
    const int t = threadIdx.x & 7;
    if (node >= N) return;
    const int per = NC >> 3;     // <= 16 (NC multiple of 16)
    const int k0 = t * per;
    int vals[16];
    int sum = 0;
#pragma unroll
    for (int j = 0; j < 16; j++) {      // independent guarded loads -> one latency round trip
        int v = 0;
        if (j < per) v = pcol[(size_t)(k0 + j) * N + node];
        vals[j] = v;
        sum += v;
    }
    int inc = sum;                       // inclusive scan across the node's 8 lanes
#pragma unroll
    for (int d = 1; d < 8; d <<= 1) {
        int v = __shfl_up(inc, d, 8);    // wave-uniform; sources within same 8-group
        if (t >= d) inc += v;
    }
    int run = inc - sum;                 // exclusive base for this thread's chunk span
#pragma unroll
    for (int j = 0; j < 16; j++) {
        if (j < per) {
            pcol[(size_t)(k0 + j) * N + node] = (u16)run;
            run += vals[j];
        }
    }
    if (t == 7) totals[node] = inc;      // lane 7's inclusive = node total

    const int perd = NCD >> 3;           // <= 8 (NCD multiple of 8)
    int s = 0;
#pragma unroll
    for (int j = 0; j < 8; j++) {
        if (j < perd) s += pdeg[(size_t)(t * perd + j) * N + node];
    }
    s += __shfl_xor(s, 1);
    s += __shfl_xor(s, 2);
    s += __shfl_xor(s, 4);
    if (t == 0) dis[node] = rsqrtf((float)(s + 1));  // +1 self loop; always > 0
}

// Phase A': per-256-node block sums of totals.
__global__ __launch_bounds__(256) void bsum_kernel(const int* __restrict__ totals,
                                                   int* __restrict__ bsum, int N) {
    __shared__ int red[256];
    int i = blockIdx.x * 256 + threadIdx.x;
    red[threadIdx.x] = (i < N) ? totals[i] : 0;
    __syncthreads();
#pragma unroll
    for (int off = 128; off > 0; off >>= 1) {
        if (threadIdx.x < off) red[threadIdx.x] += red[threadIdx.x + off];
        __syncthreads();
    }
    if (threadIdx.x == 0) bsum[blockIdx.x] = red[0];
}

// Phase B: single-block exclusive scan over nblk block sums (nblk <= 1024).
__global__ __launch_bounds__(1024) void scan_bsum_kernel(int* __restrict__ bsum, int nblk) {
    __shared__ int part[1024];
    int tid = threadIdx.x;
    int v = (tid < nblk) ? bsum[tid] : 0;
    part[tid] = v;
    __syncthreads();
    for (int off = 1; off < 1024; off <<= 1) {
        int t = (tid >= off) ? part[tid - off] : 0;
        __syncthreads();
        part[tid] += t;
        __syncthreads();
    }
    if (tid < nblk) bsum[tid] = part[tid] - v;   // exclusive
}

// Phase C: rowptr[i] = bsum[b] + block-exclusive-scan(tot); rowptr[N] = E.
__global__ __launch_bounds__(256) void rowptr_kernel(const int* __restrict__ totals,
                                                     const int* __restrict__ bsum,
                                                     int* __restrict__ rowptr, int N, int E) {
    __shared__ int part[256];
    int tid = threadIdx.x;
    int i = blockIdx.x * 256 + tid;
    int v = (i < N) ? totals[i] : 0;
    part[tid] = v;
    __syncthreads();
    for (int off = 1; off < 256; off <<= 1) {
        int t = (tid >= off) ? part[tid - off] : 0;
        __syncthreads();
        part[tid] += t;
        __syncthreads();
    }
    if (i < N) rowptr[i] = bsum[blockIdx.x] + part[tid] - v;
    if (i == 0) rowptr[N] = E;
}

// ---------------- CSR fill from partitioned pairs; per-edge base gathers; u16 csr -----------
__global__ __launch_bounds__(256) void fill_kernel(const u32* __restrict__ pairs,
                                                   const int* __restrict__ rof,
                                                   const int* __restrict__ rowptr,
                                                   const u16* __restrict__ pcol,
                                                   u16* __restrict__ csr,
                                                   int N, int cpb) {
    __shared__ alignas(16) int hist[RS];
    const int kc = blockIdx.x, r = blockIdx.y, tid = threadIdx.x;
    const int rbase = r << RSH;
    for (int j = tid; j < RS / 4; j += 256) ((int4*)hist)[j] = make_int4(0, 0, 0, 0);
    __syncthreads();
    for (int g = 0; g < GP; g++) {
        const int kp = kc * GP + g;
        const size_t base = (size_t)kp * cpb;
        const int s = rof[kp*16 + r], e = rof[kp*16 + r + 1];
        for (int i = s + tid; i < e; i += 256) {
            u32 p = pairs[base + i];
            int c = (int)(p & 0xFFFFu);
            int src = (int)(p >> 16);
            int loc = atomicAdd(&hist[c - rbase], 1);
            int pos = rowptr[c] + (int)pcol[(size_t)kc * N + c] + loc;
            csr[pos] = (u16)src;
        }
    }
}

// ---------------- W transpose+convert, ONCE; also zero the h pad-row (index N, all slabs) ---
__global__ __launch_bounds__(256) void wconv_kernel(const float* __restrict__ W1,
                                                    const float* __restrict__ W2,
                                                    u16* __restrict__ wt1,
                                                    u16* __restrict__ wt2,
                                                    u16* __restrict__ h, int N) {
    int i = blockIdx.x * 256 + threadIdx.x;   // i = n*128 + k
    int n = i >> 7, k = i & 127;
    wt1[i] = f32_to_bf16(W1[k * 128 + n]);
    wt2[i] = f32_to_bf16(W2[k * 128 + n]);
    if (i < 128) {                             // zero pad-row: 4 slabs x 32 u16
        int s = i >> 5, c = i & 31;
        h[(size_t)s * ((size_t)(N + 1) * 32) + (size_t)N * 32 + c] = 0;
    }
}

// ---------------- dense transform: H' = dis .* (X @ W)  (f32 in, bf16 MFMA, bf16 out) --------
// Writes h in SLAB layout: h[slice][node][32ch], slice = channel>>5. Each slab is
// (N+1)*64B ~ 3.2MB -> fits one XCD's 4MB L2 for the sliced agg (R13 redesign).
__global__ __launch_bounds__(256) void gemm_xw(const float* __restrict__ X,
                                               const u16* __restrict__ Wt,  // [128][128] bf16, transposed
                                               const float* __restrict__ dis,
                                               u16* __restrict__ H, int M) {
    __shared__ u16 Ws[128 * LDS_S];
    const int tid = threadIdx.x;
    // stage 32KB pre-converted Wt: 2048 16B chunks, 8 per thread, no ALU conversion
    for (int c = tid; c < 2048; c += 256) {
        int row = c >> 4, ch = c & 15;
        *(uint4*)(&Ws[row * LDS_S + ch * 8]) = *(const uint4*)(Wt + row * 128 + ch * 8);
    }
    __syncthreads();

    const int lane = tid & 63, wave = tid >> 6;
    const int quad = lane >> 4, r = lane & 15;
    int arow = blockIdx.x * 64 + wave * 16 + r;        // A-operand row (m = lane&15)
    if (arow >= M) arow = M - 1;
    const float* xrow = X + (size_t)arow * 128;

    float4v acc[8];
#pragma unroll
    for (int i = 0; i < 8; i++) acc[i] = (float4v)(0.0f);

#pragma unroll
    for (int kk = 0; kk < 4; kk++) {
        const int k0 = kk * 32 + quad * 8;             // a[j] = A[m][k0+j]
        float4 x0 = *(const float4*)(xrow + k0);
        float4 x1 = *(const float4*)(xrow + k0 + 4);
        short8 a;
        a[0] = (short)f32_to_bf16(x0.x); a[1] = (short)f32_to_bf16(x0.y);
        a[2] = (short)f32_to_bf16(x0.z); a[3] = (short)f32_to_bf16(x0.w);
        a[4] = (short)f32_to_bf16(x1.x); a[5] = (short)f32_to_bf16(x1.y);
        a[6] = (short)f32_to_bf16(x1.z); a[7] = (short)f32_to_bf16(x1.w);
#pragma unroll
        for (int nt = 0; nt < 8; nt++) {
            short8 b = *(const short8*)(&Ws[(nt * 16 + r) * LDS_S + k0]);
            acc[nt] = __builtin_amdgcn_mfma_f32_16x16x32_bf16(a, b, acc[nt], 0, 0, 0);
        }
    }

    // C/D layout: col = lane&15 (=r), row-in-tile = quad*4 + reg
    // slab write: channel c = nt*16+r -> slab s=nt>>1, within-slab ch = (nt&1)*16+r
    const size_t slabstride = (size_t)(M + 1) * 32;     // u16 units
    const int orow0 = blockIdx.x * 64 + wave * 16 + quad * 4;
#pragma unroll
    for (int reg = 0; reg < 4; reg++) {
        int gr = orow0 + reg;
        if (gr < M) {
            float dscale = dis[gr];
#pragma unroll
            for (int nt = 0; nt < 8; nt++) {
                H[(size_t)(nt >> 1) * slabstride + (size_t)gr * 32 + (nt & 1) * 16 + r] =
                    f32_to_bf16(dscale * acc[nt][reg]);
            }
        }
    }
}

// ---------------- aggregation: out[i] = dis[i]*(sum h'[src] + h'[i]) + b --------------------
// R13/R14: channel-sliced + XCD-affine. Evidence: MLP 2->4->8 in flight gave +2%/-11% at
// fixed 151MB FETCH => footprint-bound (h 12.8MB >> 4MB per-XCD L2; random graph => every
// XCD refetches ~all of h). Channels are separable, so: h stored as 4 slabs
// h[s][node][32ch] (3.2MB each, L2-resident); round-robin bid%8->XCD puts slice s on XCD
// pair {2s,2s+1} (half the nodes each). Per node: 4 lanes x 8 channels, in-lane serial
// accumulation over edges (NO cross-lane reduce), 16 nodes/wave, 4x unroll. Branchless
// edge guard: OOB lanes gather the zeroed pad-row (index N). R14 hardening: csr index
// clamped to >= e (deg==0 lanes previously computed csr[e-1] -> csr[-1] possible).
__device__ inline void acc_add(float2* a, uint4 v) {
    a[0].x += bf16_lo(v.x); a[0].y += bf16_hi(v.x);
    a[1].x += bf16_lo(v.y); a[1].y += bf16_hi(v.y);
    a[2].x += bf16_lo(v.z); a[2].y += bf16_hi(v.z);
    a[3].x += bf16_lo(v.w); a[3].y += bf16_hi(v.w);
}

__global__ __launch_bounds__(256) void agg_kernel(const u16* __restrict__ h,
                                                  const float* __restrict__ dis,
                                                  const int* __restrict__ rowptr,
                                                  const u16* __restrict__ csr,
                                                  const float* __restrict__ bias,
                                                  float* __restrict__ out,
                                                  int N, int do_relu) {
    const int wave = threadIdx.x >> 6, lane = threadIdx.x & 63;
    const int sub = blockIdx.x & 7;        // == XCD id under round-robin dispatch
    const int slice = sub >> 1;            // slice s on XCD pair {2s, 2s+1}
    const int half = sub & 1;              // the pair splits the node range
    const int g = lane >> 2;               // node sub-index 0..15
    const int q = lane & 3;                // 16B quarter of the 64B slice row
    const int q8 = q * 8;                  // u16 offset within slice row
    const int node = ((int)(blockIdx.x >> 3) * 2 + half) * 64 + wave * 16 + g;

    const size_t slabstride = (size_t)(N + 1) * 32;   // u16 units
    const u16* slab = h + (size_t)slice * slabstride;

    int e = 0, deg = 0;
    if (node < N) { e = rowptr[node]; deg = rowptr[node + 1] - e; }
    const int last = max(deg - 1, 0);      // safe clamp (deg==0 lanes stay at csr[e])

    // wave-max degree (lanes within a 4-group share deg, so xor 4/8/16/32 reduces all 16)
    int md = deg;
    md = max(md, __shfl_xor(md, 4));
    md = max(md, __shfl_xor(md, 8));
    md = max(md, __shfl_xor(md, 16));
    md = max(md, __shfl_xor(md, 32));

    float2 acc[4];
#pragma unroll
    for (int i = 0; i < 4; i++) acc[i] = make_float2(0.0f, 0.0f);

    int j = 0;
    for (; j + 4 <= md; j += 4) {          // 4 independent gathers in flight per lane
        int i0 = e + min(j,     last);
        int i1 = e + min(j + 1, last);
        int i2 = e + min(j + 2, last);
        int i3 = e + min(j + 3, last);
        int s0 = (int)csr[i0], s1 = (int)csr[i1], s2 = (int)csr[i2], s3 = (int)csr[i3];
        s0 = (j     < deg) ? s0 : N;       // OOB -> zero pad-row
        s1 = (j + 1 < deg) ? s1 : N;
        s2 = (j + 2 < deg) ? s2 : N;
        s3 = (j + 3 < deg) ? s3 : N;
        uint4 v0 = *(const uint4*)(slab + (size_t)s0 * 32 + q8);
        uint4 v1 = *(const uint4*)(slab + (size_t)s1 * 32 + q8);
        uint4 v2 = *(const uint4*)(slab + (size_t)s2 * 32 + q8);
        uint4 v3 = *(const uint4*)(slab + (size_t)s3 * 32 + q8);
        acc_add(acc, v0); acc_add(acc, v1); acc_add(acc, v2); acc_add(acc, v3);
    }
    for (; j < md; ++j) {
        int i0 = e + min(j, last);
        int s0 = (int)csr[i0];
        s0 = (j < deg) ? s0 : N;
        uint4 v0 = *(const uint4*)(slab + (size_t)s0 * 32 + q8);
        acc_add(acc, v0);
    }

    if (node < N) {
        uint4 vs = *(const uint4*)(slab + (size_t)node * 32 + q8);   // self row (L2-hit)
        const float di = dis[node];
        const float* bp = bias + slice * 32 + q8;
        float4 c0 = *(const float4*)bp;
        float4 c1 = *(const float4*)(bp + 4);
        float r0 = di * (acc[0].x + bf16_lo(vs.x)) + c0.x;
        float r1 = di * (acc[0].y + bf16_hi(vs.x)) + c0.y;
        float r2 = di * (acc[1].x + bf16_lo(vs.y)) + c0.z;
        float r3 = di * (acc[1].y + bf16_hi(vs.y)) + c0.w;
        float r4 = di * (acc[2].x + bf16_lo(vs.z)) + c1.x;
        float r5 = di * (acc[2].y + bf16_hi(vs.z)) + c1.y;
        float r6 = di * (acc[3].x + bf16_lo(vs.w)) + c1.z;
        float r7 = di * (acc[3].y + bf16_hi(vs.w)) + c1.w;
        if (do_relu) {
            r0 = fmaxf(r0, 0.0f); r1 = fmaxf(r1, 0.0f); r2 = fmaxf(r2, 0.0f); r3 = fmaxf(r3, 0.0f);
            r4 = fmaxf(r4, 0.0f); r5 = fmaxf(r5, 0.0f); r6 = fmaxf(r6, 0.0f); r7 = fmaxf(r7, 0.0f);
        }
        // nontemporal: out streams 25.6MB; keep it from evicting the L2-resident slab
        float* op = out + (size_t)node * 128 + slice * 32 + q8;
        float4v w0; w0[0] = r0; w0[1] = r1; w0[2] = r2; w0[3] = r3;
        float4v w1; w1[0] = r4; w1[1] = r5; w1[2] = r6; w1[3] = r7;
        __builtin_nontemporal_store(w0, (float4v*)op);
        __builtin_nontemporal_store(w1, (float4v*)(op + 4));
    }
}

// ---------------- launch ----------------

extern "C" void kernel_launch(void* const* d_in, const int* in_sizes, int n_in,
                              void* d_out, int out_size, void* d_ws, size_t ws_size,
                              hipStream_t stream) {
    const float* x  = (const float*)d_in[0];   // [N,128] f32
    const int*   ei = (const int*)d_in[1];     // [2,E] int32
    const float* W1 = (const float*)d_in[2];   // [128,128] f32
    const float* b1 = (const float*)d_in[3];   // [128] f32
    const float* W2 = (const float*)d_in[4];
    const float* b2 = (const float*)d_in[5];
    float* out = (float*)d_out;                // [N,128] f32

    const int N = in_sizes[0] / 128;
    const int E = in_sizes[1] / 2;
    const int* er = ei;        // sources (gathered)
    const int* ec = ei + E;    // destinations (scattered)

    char* ws = (char*)d_ws;
    size_t off = 0;
    auto alloc = [&](size_t b) { size_t o = off; off += (b + 255) & ~(size_t)255; return o; };
    size_t o_tot  = alloc((size_t)N * 4);
    size_t o_rp   = alloc((size_t)(N + 1) * 4);
    size_t o_dis  = alloc((size_t)N * 4);
    size_t o_bsum = alloc((size_t)1024 * 4);
    size_t o_rof  = alloc((size_t)1024 * 16 * 4);
    size_t o_srof = alloc((size_t)1024 * 16 * 4);
    size_t o_csr  = alloc((size_t)E * 2);
    size_t o_h    = alloc((size_t)(N + 1) * 128 * 2);   // 4 slabs x (N+1) x 64B
    size_t o_wt1  = alloc((size_t)128 * 128 * 2);
    size_t o_wt2  = alloc((size_t)128 * 128 * 2);
    size_t o_prs  = alloc((size_t)(E + 1024) * 4);
    size_t o_srcp = alloc((size_t)(E + 1024) * 2);

    size_t rem = (ws_size > off + 4096) ? (ws_size - off - 4096) : 0;
    long long nc = (long long)(rem / (3 * (size_t)N));
    if (nc > 128) nc = 128;
    if (nc < 16) nc = 16;
    nc &= ~15LL;                              // NC multiple of 16 (chunk_scan needs NC%16==0)
    const int NC = (int)nc, NCD = NC / 2;
    const int NCP = NC * GP;                 // partition chunks
    const int GPD = NCP / NCD;               // = 16

    size_t o_pcol = alloc((size_t)NC * N * 2);
    size_t o_pdeg = alloc((size_t)NCD * N * 2);

    int*   tot  = (int*)(ws + o_tot);
    int*   rp   = (int*)(ws + o_rp);
    float* dis  = (float*)(ws + o_dis);
    int*   bsum = (int*)(ws + o_bsum);
    int*   rof  = (int*)(ws + o_rof);
    int*   srof = (int*)(ws + o_srof);
    u16*   csr  = (u16*)(ws + o_csr);
    u16*   h    = (u16*)(ws + o_h);
    u16*   wt1  = (u16*)(ws + o_wt1);
    u16*   wt2  = (u16*)(ws + o_wt2);
    u32*   prs  = (u32*)(ws + o_prs);
    u16*   srcp = (u16*)(ws + o_srcp);
    u16*   pcol = (u16*)(ws + o_pcol);
    u16*   pdeg = (u16*)(ws + o_pdeg);

    const int NR = (N + RS - 1) / RS;        // 7 for N=50000 (must be <= 15)
    const int cpb  = (E + NCP - 1) / NCP;
    const int nblk = (N + 255) / 256;        // 196 (<= 1024 required)
    const int csblk = (int)(((size_t)N * 8 + 255) / 256);
    // agg grid: (chunk-pairs) x 8 XCD-groups; chunk = 64 nodes
    const int nchunk = (N + 63) / 64;
    const int aggblk = ((nchunk + 1) / 2) * 8;

    wconv_kernel<<<64, 256, 0, stream>>>(W1, W2, wt1, wt2, h, N);
    partition_kernel<<<NCP, 256, 0, stream>>>(er, ec, prs, srcp, rof, srof, E, cpb, NR);
    colhist_kernel<<<dim3(NC, NR), 256, 0, stream>>>(prs, rof, pcol, N, cpb);
    deghist_kernel<<<dim3(NCD, NR), 256, 0, stream>>>(srcp, srof, pdeg, N, cpb, GPD);
    chunk_scan_kernel<<<csblk, 256, 0, stream>>>(pcol, pdeg, tot, dis, N, NC, NCD);
    bsum_kernel<<<nblk, 256, 0, stream>>>(tot, bsum, N);
    scan_bsum_kernel<<<1, 1024, 0, stream>>>(bsum, nblk);
    rowptr_kernel<<<nblk, 256, 0, stream>>>(tot, bsum, rp, N, E);
    fill_kernel<<<dim3(NC, NR), 256, 0, stream>>>(prs, rof, rp, pcol, csr, N, cpb);

    // layer 1: h' = dis.*bf16(x@W1) ; d_out = relu(agg(h') + b1)
    gemm_xw<<<(N + 63) / 64, 256, 0, stream>>>(x, wt1, dis, h, N);
    agg_kernel<<<aggblk, 256, 0, stream>>>(h, dis, rp, csr, b1, out, N, 1);

    // layer 2: h' = dis.*bf16(d_out@W2) ; d_out = agg(h') + b2
    gemm_xw<<<(N + 63) / 64, 256, 0, stream>>>(out, wt2, dis, h, N);
    agg_kernel<<<aggblk, 256, 0, stream>>>(h, dis, rp, csr, b2, out, N, 0);
}

// Round 5
// 273.259 us; speedup vs baseline: 1.1287x; 1.0245x over previous
//
#include <hip/hip_runtime.h>

typedef unsigned short u16;
typedef unsigned int u32;
typedef __attribute__((ext_vector_type(8))) short short8;
typedef __attribute__((ext_vector_type(4))) float float4v;

#define LDS_S 136   // padded row stride (bf16 elems) for W tile in LDS (breaks 256B bank stride)
#define RS 8192     // node-range size (32KB LDS int counters)
#define RSH 13
#define GP 8        // partition chunks per col-chunk

__device__ inline float bf16_lo(u32 v) { return __uint_as_float(v << 16); }
__device__ inline float bf16_hi(u32 v) { return __uint_as_float(v & 0xFFFF0000u); }

__device__ inline u16 f32_to_bf16(float f) {
    u32 u = __float_as_uint(f);
    u32 r = u + 0x7FFFu + ((u >> 16) & 1u);   // round-to-nearest-even
    return (u16)(r >> 16);
}

// ---------------- P0: partition edges by col-range (pairs) and src-range (srcp) -------------
__global__ __launch_bounds__(256) void partition_kernel(const int* __restrict__ er,
                                                        const int* __restrict__ ec,
                                                        u32* __restrict__ pairs,
                                                        u16* __restrict__ srcp,
                                                        int* __restrict__ rof,
                                                        int* __restrict__ srof,
                                                        int E, int cpb, int NR) {
    __shared__ int cnt[16], scnt[16];
    const int k = blockIdx.x, tid = threadIdx.x;
    const int e0 = k * cpb, e1 = min(e0 + cpb, E);
    if (tid < 16) { cnt[tid] = 0; scnt[tid] = 0; }
    __syncthreads();
    for (int e = e0 + tid; e < e1; e += 256) {
        atomicAdd(&cnt[ec[e] >> RSH], 1);
        atomicAdd(&scnt[er[e] >> RSH], 1);
    }
    __syncthreads();
    if (tid == 0) {
        int run = 0;
        for (int r = 0; r < NR; r++) { int c = cnt[r]; rof[k*16 + r] = run; cnt[r] = run; run += c; }
        rof[k*16 + NR] = run;
        run = 0;
        for (int r = 0; r < NR; r++) { int c = scnt[r]; srof[k*16 + r] = run; scnt[r] = run; run += c; }
        srof[k*16 + NR] = run;
    }
    __syncthreads();
    const size_t base = (size_t)k * cpb;
    for (int e = e0 + tid; e < e1; e += 256) {
        int s = er[e], c = ec[e];
        int slot = atomicAdd(&cnt[c >> RSH], 1);
        pairs[base + slot] = ((u32)s << 16) | (u32)c;
        int slot2 = atomicAdd(&scnt[s >> RSH], 1);
        srcp[base + slot2] = (u16)s;
    }
}

// ---------------- col histogram over partitioned pairs -> pcol u16 --------------------------
__global__ __launch_bounds__(256) void colhist_kernel(const u32* __restrict__ pairs,
                                                      const int* __restrict__ rof,
                                                      u16* __restrict__ pcol,
                                                      int N, int cpb) {
    __shared__ alignas(16) int hist[RS];
    const int kc = blockIdx.x, r = blockIdx.y, tid = threadIdx.x;
    const int rbase = r << RSH;
    const int rcount = min(RS, N - rbase);
    for (int j = tid; j < RS / 4; j += 256) ((int4*)hist)[j] = make_int4(0, 0, 0, 0);
    __syncthreads();
    for (int g = 0; g < GP; g++) {
        const int kp = kc * GP + g;
        const size_t base = (size_t)kp * cpb;
        const int s = rof[kp*16 + r], e = rof[kp*16 + r + 1];
        for (int i = s + tid; i < e; i += 256) {
            u32 p = pairs[base + i];
            atomicAdd(&hist[(int)(p & 0xFFFFu) - rbase], 1);
        }
    }
    __syncthreads();
    for (int j = tid; j < rcount; j += 256)
        pcol[(size_t)kc * N + rbase + j] = (u16)hist[j];
}

// ---------------- deg histogram over partitioned srcs -> pdeg u16 ---------------------------
__global__ __launch_bounds__(256) void deghist_kernel(const u16* __restrict__ srcp,
                                                      const int* __restrict__ srof,
                                                      u16* __restrict__ pdeg,
                                                      int N, int cpb, int GPD) {
    __shared__ alignas(16) int hist[RS];
    const int kd = blockIdx.x, r = blockIdx.y, tid = threadIdx.x;
    const int rbase = r << RSH;
    const int rcount = min(RS, N - rbase);
    for (int j = tid; j < RS / 4; j += 256) ((int4*)hist)[j] = make_int4(0, 0, 0, 0);
    __syncthreads();
    for (int g = 0; g < GPD; g++) {
        const int kp = kd * GPD + g;
        const size_t base = (size_t)kp * cpb;
        const int s = srof[kp*16 + r], e = srof[kp*16 + r + 1];
        for (int i = s + tid; i < e; i += 256)
            atomicAdd(&hist[(int)srcp[base + i] - rbase], 1);
    }
    __syncthreads();
    for (int j = tid; j < rcount; j += 256)
        pdeg[(size_t)kd * N + rbase + j] = (u16)hist[j];
}

// ---------------- chunk scan: 8 threads/node, register-batched loads + shfl prefix ----------
// totals[] = TRUE degree (padding applied downstream in bsum/rowptr).
__global__ __launch_bounds__(256) void chunk_scan_kernel(u16* __restrict__ pcol,
                                                         const u16* __restrict__ pdeg,
                                                         int* __restrict__ totals,
                                                         float* __restrict__ dis,
                                                         int N, int NC, int NCD) {
    const int gid = blockIdx.x * 256 + threadIdx.x;
    const int node = gid >> 3;
    const int t = threadIdx.x & 7;
    if (node >= N) return;
    const int per = NC >> 3;     // <= 16 (NC multiple of 16)
    const int k0 = t * per;
    int vals[16];
    int sum = 0;
#pragma unroll
    for (int j = 0; j < 16; j++) {      // independent guarded loads -> one latency round trip
        int v = 0;
        if (j < per) v = pcol[(size_t)(k0 + j) * N + node];
        vals[j] = v;
        sum += v;
    }
    int inc = sum;                       // inclusive scan across the node's 8 lanes
#pragma unroll
    for (int d = 1; d < 8; d <<= 1) {
        int v = __shfl_up(inc, d, 8);    // wave-uniform; sources within same 8-group
        if (t >= d) inc += v;
    }
    int run = inc - sum;                 // exclusive base for this thread's chunk span
#pragma unroll
    for (int j = 0; j < 16; j++) {
        if (j < per) {
            pcol[(size_t)(k0 + j) * N + node] = (u16)run;
            run += vals[j];
        }
    }
    if (t == 7) totals[node] = inc;      // lane 7's inclusive = node total (true deg)

    const int perd = NCD >> 3;           // <= 8 (NCD multiple of 8)
    int s = 0;
#pragma unroll
    for (int j = 0; j < 8; j++) {
        if (j < perd) s += pdeg[(size_t)(t * perd + j) * N + node];
    }
    s += __shfl_xor(s, 1);
    s += __shfl_xor(s, 2);
    s += __shfl_xor(s, 4);
    if (t == 0) dis[node] = rsqrtf((float)(s + 1));  // +1 self loop; always > 0
}

// Phase A': per-256-node block sums of PADDED totals (CSR rows padded to multiple of 4).
__global__ __launch_bounds__(256) void bsum_kernel(const int* __restrict__ totals,
                                                   int* __restrict__ bsum, int N) {
    __shared__ int red[256];
    int i = blockIdx.x * 256 + threadIdx.x;
    red[threadIdx.x] = (i < N) ? ((totals[i] + 3) & ~3) : 0;
    __syncthreads();
#pragma unroll
    for (int off = 128; off > 0; off >>= 1) {
        if (threadIdx.x < off) red[threadIdx.x] += red[threadIdx.x + off];
        __syncthreads();
    }
    if (threadIdx.x == 0) bsum[blockIdx.x] = red[0];
}

// Phase B: single-block exclusive scan over nblk block sums (nblk <= 1024).
__global__ __launch_bounds__(1024) void scan_bsum_kernel(int* __restrict__ bsum, int nblk) {
    __shared__ int part[1024];
    int tid = threadIdx.x;
    int v = (tid < nblk) ? bsum[tid] : 0;
    part[tid] = v;
    __syncthreads();
    for (int off = 1; off < 1024; off <<= 1) {
        int t = (tid >= off) ? part[tid - off] : 0;
        __syncthreads();
        part[tid] += t;
        __syncthreads();
    }
    if (tid < nblk) bsum[tid] = part[tid] - v;   // exclusive
}

// Phase C: rowptr over PADDED degrees; writes the <=3 pad slots per node with id N
// (pad id -> zeroed pad row, so agg needs NO bounds logic and e is always 4-aligned
// -> csr ids load as dwordx2 pairs). rowptr[N] = padded total.
__global__ __launch_bounds__(256) void rowptr_kernel(const int* __restrict__ totals,
                                                     const int* __restrict__ bsum,
                                                     int* __restrict__ rowptr,
                                                     u16* __restrict__ csr, int N) {
    __shared__ int part[256];
    int tid = threadIdx.x;
    int i = blockIdx.x * 256 + tid;
    int td = (i < N) ? totals[i] : 0;
    int v = (td + 3) & ~3;                 // padded degree
    part[tid] = v;
    __syncthreads();
    for (int off = 1; off < 256; off <<= 1) {
        int t = (tid >= off) ? part[tid - off] : 0;
        __syncthreads();
        part[tid] += t;
        __syncthreads();
    }
    if (i < N) {
        int rp = bsum[blockIdx.x] + part[tid] - v;   // padded exclusive base
        rowptr[i] = rp;
        for (int p = td; p < v; p++) csr[rp + p] = (u16)N;   // <=3 pad slots
        if (i == N - 1) rowptr[N] = bsum[blockIdx.x] + part[tid];
    }
}

// ---------------- CSR fill from partitioned pairs; per-edge base gathers; u16 csr -----------
__global__ __launch_bounds__(256) void fill_kernel(const u32* __restrict__ pairs,
                                                   const int* __restrict__ rof,
                                                   const int* __restrict__ rowptr,
                                                   const u16* __restrict__ pcol,
                                                   u16* __restrict__ csr,
                                                   int N, int cpb) {
    __shared__ alignas(16) int hist[RS];
    const int kc = blockIdx.x, r = blockIdx.y, tid = threadIdx.x;
    const int rbase = r << RSH;
    for (int j = tid; j < RS / 4; j += 256) ((int4*)hist)[j] = make_int4(0, 0, 0, 0);
    __syncthreads();
    for (int g = 0; g < GP; g++) {
        const int kp = kc * GP + g;
        const size_t base = (size_t)kp * cpb;
        const int s = rof[kp*16 + r], e = rof[kp*16 + r + 1];
        for (int i = s + tid; i < e; i += 256) {
            u32 p = pairs[base + i];
            int c = (int)(p & 0xFFFFu);
            int src = (int)(p >> 16);
            int loc = atomicAdd(&hist[c - rbase], 1);
            int pos = rowptr[c] + (int)pcol[(size_t)kc * N + c] + loc;
            csr[pos] = (u16)src;
        }
    }
}

// ---------------- W transpose+convert, ONCE; also zero the h pad-row (index N, all slabs) ---
__global__ __launch_bounds__(256) void wconv_kernel(const float* __restrict__ W1,
                                                    const float* __restrict__ W2,
                                                    u16* __restrict__ wt1,
                                                    u16* __restrict__ wt2,
                                                    u16* __restrict__ h, int N) {
    int i = blockIdx.x * 256 + threadIdx.x;   // i = n*128 + k
    int n = i >> 7, k = i & 127;
    wt1[i] = f32_to_bf16(W1[k * 128 + n]);
    wt2[i] = f32_to_bf16(W2[k * 128 + n]);
    if (i < 128) {                             // zero pad-row: 4 slabs x 32 u16
        int s = i >> 5, c = i & 31;
        h[(size_t)s * ((size_t)(N + 1) * 32) + (size_t)N * 32 + c] = 0;
    }
}

// ---------------- dense transform: H' = dis .* (X @ W)  (f32 in, bf16 MFMA, bf16 out) --------
// Writes h in SLAB layout: h[slice][node][32ch], slice = channel>>5. Each slab is
// (N+1)*64B ~ 3.2MB -> fits one XCD's 4MB L2 for the sliced agg (R13 redesign).
__global__ __launch_bounds__(256) void gemm_xw(const float* __restrict__ X,
                                               const u16* __restrict__ Wt,  // [128][128] bf16, transposed
                                               const float* __restrict__ dis,
                                               u16* __restrict__ H, int M) {
    __shared__ u16 Ws[128 * LDS_S];
    const int tid = threadIdx.x;
    // stage 32KB pre-converted Wt: 2048 16B chunks, 8 per thread, no ALU conversion
    for (int c = tid; c < 2048; c += 256) {
        int row = c >> 4, ch = c & 15;
        *(uint4*)(&Ws[row * LDS_S + ch * 8]) = *(const uint4*)(Wt + row * 128 + ch * 8);
    }
    __syncthreads();

    const int lane = tid & 63, wave = tid >> 6;
    const int quad = lane >> 4, r = lane & 15;
    int arow = blockIdx.x * 64 + wave * 16 + r;        // A-operand row (m = lane&15)
    if (arow >= M) arow = M - 1;
    const float* xrow = X + (size_t)arow * 128;

    float4v acc[8];
#pragma unroll
    for (int i = 0; i < 8; i++) acc[i] = (float4v)(0.0f);

#pragma unroll
    for (int kk = 0; kk < 4; kk++) {
        const int k0 = kk * 32 + quad * 8;             // a[j] = A[m][k0+j]
        float4 x0 = *(const float4*)(xrow + k0);
        float4 x1 = *(const float4*)(xrow + k0 + 4);
        short8 a;
        a[0] = (short)f32_to_bf16(x0.x); a[1] = (short)f32_to_bf16(x0.y);
        a[2] = (short)f32_to_bf16(x0.z); a[3] = (short)f32_to_bf16(x0.w);
        a[4] = (short)f32_to_bf16(x1.x); a[5] = (short)f32_to_bf16(x1.y);
        a[6] = (short)f32_to_bf16(x1.z); a[7] = (short)f32_to_bf16(x1.w);
#pragma unroll
        for (int nt = 0; nt < 8; nt++) {
            short8 b = *(const short8*)(&Ws[(nt * 16 + r) * LDS_S + k0]);
            acc[nt] = __builtin_amdgcn_mfma_f32_16x16x32_bf16(a, b, acc[nt], 0, 0, 0);
        }
    }

    // C/D layout: col = lane&15 (=r), row-in-tile = quad*4 + reg
    // slab write: channel c = nt*16+r -> slab s=nt>>1, within-slab ch = (nt&1)*16+r
    const size_t slabstride = (size_t)(M + 1) * 32;     // u16 units
    const int orow0 = blockIdx.x * 64 + wave * 16 + quad * 4;
#pragma unroll
    for (int reg = 0; reg < 4; reg++) {
        int gr = orow0 + reg;
        if (gr < M) {
            float dscale = dis[gr];
#pragma unroll
            for (int nt = 0; nt < 8; nt++) {
                H[(size_t)(nt >> 1) * slabstride + (size_t)gr * 32 + (nt & 1) * 16 + r] =
                    f32_to_bf16(dscale * acc[nt][reg]);
            }
        }
    }
}

// ---------------- aggregation: out[i] = dis[i]*(sum h'[src] + h'[i]) + b --------------------
// R15: padded-CSR inner loop. R14 counters: FETCH 151->30MB (slab/XCD-affinity confirmed)
// but dur only 48.7->47.4: HBM 15%, VALU 40% => issue/chain-bound, not BW. Old loop paid
// ~110 VALU/4 edges (clamps, cndmasks, scalar csr loads) + 2 serialized L2 trips per iter
// + ~27% wave-max-degree pad waste. Now: CSR rows padded to %4 with pad-id N (-> zero row),
// so ids load as dwordx2 (8 ids / 2 loads), zero bounds logic, and the loop is per-GROUP
// divergent (no shfl in loop => exec-mask divergence safe; pad waste ~5%). csr loads are
// independent of gathers -> chain broken; 8 gathers in flight, <64 VGPR.
__device__ inline void acc_add(float2* a, uint4 v) {
    a[0].x += bf16_lo(v.x); a[0].y += bf16_hi(v.x);
    a[1].x += bf16_lo(v.y); a[1].y += bf16_hi(v.y);
    a[2].x += bf16_lo(v.z); a[2].y += bf16_hi(v.z);
    a[3].x += bf16_lo(v.w); a[3].y += bf16_hi(v.w);
}

__global__ __launch_bounds__(256) void agg_kernel(const u16* __restrict__ h,
                                                  const float* __restrict__ dis,
                                                  const int* __restrict__ rowptr,
                                                  const u16* __restrict__ csr,
                                                  const float* __restrict__ bias,
                                                  float* __restrict__ out,
                                                  int N, int do_relu) {
    const int wave = threadIdx.x >> 6, lane = threadIdx.x & 63;
    const int sub = blockIdx.x & 7;        // == XCD id under round-robin dispatch
    const int slice = sub >> 1;            // slice s on XCD pair {2s, 2s+1}
    const int half = sub & 1;              // the pair splits the node range
    const int g = lane >> 2;               // node sub-index 0..15
    const int q = lane & 3;                // 16B quarter of the 64B slice row
    const int node = ((int)(blockIdx.x >> 3) * 2 + half) * 64 + wave * 16 + g;
    if (node >= N) return;                 // group-uniform exit; no shfl/barrier below

    const size_t slabstride = (size_t)(N + 1) * 32;   // u16 units
    const u16* slab = h + (size_t)slice * slabstride + q * 8;   // per-lane base

    const int e = rowptr[node];            // 4-aligned by construction
    const int degp = rowptr[node + 1] - e; // padded degree (multiple of 4)

    float2 acc[4];
#pragma unroll
    for (int i = 0; i < 4; i++) acc[i] = make_float2(0.0f, 0.0f);

    int j = 0;
    for (; j + 8 <= degp; j += 8) {        // 2 id-loads + 8 independent gathers in flight
        uint2 c0 = *(const uint2*)(csr + e + j);
        uint2 c1 = *(const uint2*)(csr + e + j + 4);
        u32 a0 = c0.x & 0xFFFFu, a1 = c0.x >> 16, a2 = c0.y & 0xFFFFu, a3 = c0.y >> 16;
        u32 b0 = c1.x & 0xFFFFu, b1 = c1.x >> 16, b2 = c1.y & 0xFFFFu, b3 = c1.y >> 16;
        uint4 v0 = *(const uint4*)(slab + (size_t)a0 * 32);
        uint4 v1 = *(const uint4*)(slab + (size_t)a1 * 32);
        uint4 v2 = *(const uint4*)(slab + (size_t)a2 * 32);
        uint4 v3 = *(const uint4*)(slab + (size_t)a3 * 32);
        uint4 v4 = *(const uint4*)(slab + (size_t)b0 * 32);
        uint4 v5 = *(const uint4*)(slab + (size_t)b1 * 32);
        uint4 v6 = *(const uint4*)(slab + (size_t)b2 * 32);
        uint4 v7 = *(const uint4*)(slab + (size_t)b3 * 32);
        acc_add(acc, v0); acc_add(acc, v1); acc_add(acc, v2); acc_add(acc, v3);
        acc_add(acc, v4); acc_add(acc, v5); acc_add(acc, v6); acc_add(acc, v7);
    }
    if (j < degp) {                        // exactly 4 remaining
        uint2 c0 = *(const uint2*)(csr + e + j);
        u32 a0 = c0.x & 0xFFFFu, a1 = c0.x >> 16, a2 = c0.y & 0xFFFFu, a3 = c0.y >> 16;
        uint4 v0 = *(const uint4*)(slab + (size_t)a0 * 32);
        uint4 v1 = *(const uint4*)(slab + (size_t)a1 * 32);
        uint4 v2 = *(const uint4*)(slab + (size_t)a2 * 32);
        uint4 v3 = *(const uint4*)(slab + (size_t)a3 * 32);
        acc_add(acc, v0); acc_add(acc, v1); acc_add(acc, v2); acc_add(acc, v3);
    }

    {
        uint4 vs = *(const uint4*)(slab + (size_t)node * 32);   // self row (L2-hit)
        const float di = dis[node];
        const float* bp = bias + slice * 32 + q * 8;
        float4 cb0 = *(const float4*)bp;
        float4 cb1 = *(const float4*)(bp + 4);
        float r0 = di * (acc[0].x + bf16_lo(vs.x)) + cb0.x;
        float r1 = di * (acc[0].y + bf16_hi(vs.x)) + cb0.y;
        float r2 = di * (acc[1].x + bf16_lo(vs.y)) + cb0.z;
        float r3 = di * (acc[1].y + bf16_hi(vs.y)) + cb0.w;
        float r4 = di * (acc[2].x + bf16_lo(vs.z)) + cb1.x;
        float r5 = di * (acc[2].y + bf16_hi(vs.z)) + cb1.y;
        float r6 = di * (acc[3].x + bf16_lo(vs.w)) + cb1.z;
        float r7 = di * (acc[3].y + bf16_hi(vs.w)) + cb1.w;
        if (do_relu) {
            r0 = fmaxf(r0, 0.0f); r1 = fmaxf(r1, 0.0f); r2 = fmaxf(r2, 0.0f); r3 = fmaxf(r3, 0.0f);
            r4 = fmaxf(r4, 0.0f); r5 = fmaxf(r5, 0.0f); r6 = fmaxf(r6, 0.0f); r7 = fmaxf(r7, 0.0f);
        }
        // nontemporal: out streams 25.6MB; keep it from evicting the L2-resident slab
        float* op = out + (size_t)node * 128 + slice * 32 + q * 8;
        float4v w0; w0[0] = r0; w0[1] = r1; w0[2] = r2; w0[3] = r3;
        float4v w1; w1[0] = r4; w1[1] = r5; w1[2] = r6; w1[3] = r7;
        __builtin_nontemporal_store(w0, (float4v*)op);
        __builtin_nontemporal_store(w1, (float4v*)(op + 4));
    }
}

// ---------------- launch ----------------

extern "C" void kernel_launch(void* const* d_in, const int* in_sizes, int n_in,
                              void* d_out, int out_size, void* d_ws, size_t ws_size,
                              hipStream_t stream) {
    const float* x  = (const float*)d_in[0];   // [N,128] f32
    const int*   ei = (const int*)d_in[1];     // [2,E] int32
    const float* W1 = (const float*)d_in[2];   // [128,128] f32
    const float* b1 = (const float*)d_in[3];   // [128] f32
    const float* W2 = (const float*)d_in[4];
    const float* b2 = (const float*)d_in[5];
    float* out = (float*)d_out;                // [N,128] f32

    const int N = in_sizes[0] / 128;
    const int E = in_sizes[1] / 2;
    const int* er = ei;        // sources (gathered)
    const int* ec = ei + E;    // destinations (scattered)

    char* ws = (char*)d_ws;
    size_t off = 0;
    auto alloc = [&](size_t b) { size_t o = off; off += (b + 255) & ~(size_t)255; return o; };
    size_t o_tot  = alloc((size_t)N * 4);
    size_t o_rp   = alloc((size_t)(N + 1) * 4);
    size_t o_dis  = alloc((size_t)N * 4);
    size_t o_bsum = alloc((size_t)1024 * 4);
    size_t o_rof  = alloc((size_t)1024 * 16 * 4);
    size_t o_srof = alloc((size_t)1024 * 16 * 4);
    size_t o_csr  = alloc(((size_t)E + 4 * (size_t)N + 64) * 2);   // padded CSR (%4 per node)
    size_t o_h    = alloc((size_t)(N + 1) * 128 * 2);   // 4 slabs x (N+1) x 64B
    size_t o_wt1  = alloc((size_t)128 * 128 * 2);
    size_t o_wt2  = alloc((size_t)128 * 128 * 2);
    size_t o_prs  = alloc((size_t)(E + 1024) * 4);
    size_t o_srcp = alloc((size_t)(E + 1024) * 2);

    size_t rem = (ws_size > off + 4096) ? (ws_size - off - 4096) : 0;
    long long nc = (long long)(rem / (3 * (size_t)N));
    if (nc > 128) nc = 128;
    if (nc < 16) nc = 16;
    nc &= ~15LL;                              // NC multiple of 16 (chunk_scan needs NC%16==0)
    const int NC = (int)nc, NCD = NC / 2;
    const int NCP = NC * GP;                 // partition chunks
    const int GPD = NCP / NCD;               // = 16

    size_t o_pcol = alloc((size_t)NC * N * 2);
    size_t o_pdeg = alloc((size_t)NCD * N * 2);

    int*   tot  = (int*)(ws + o_tot);
    int*   rp   = (int*)(ws + o_rp);
    float* dis  = (float*)(ws + o_dis);
    int*   bsum = (int*)(ws + o_bsum);
    int*   rof  = (int*)(ws + o_rof);
    int*   srof = (int*)(ws + o_srof);
    u16*   csr  = (u16*)(ws + o_csr);
    u16*   h    = (u16*)(ws + o_h);
    u16*   wt1  = (u16*)(ws + o_wt1);
    u16*   wt2  = (u16*)(ws + o_wt2);
    u32*   prs  = (u32*)(ws + o_prs);
    u16*   srcp = (u16*)(ws + o_srcp);
    u16*   pcol = (u16*)(ws + o_pcol);
    u16*   pdeg = (u16*)(ws + o_pdeg);

    const int NR = (N + RS - 1) / RS;        // 7 for N=50000 (must be <= 15)
    const int cpb  = (E + NCP - 1) / NCP;
    const int nblk = (N + 255) / 256;        // 196 (<= 1024 required)
    const int csblk = (int)(((size_t)N * 8 + 255) / 256);
    // agg grid: (chunk-pairs) x 8 XCD-groups; chunk = 64 nodes
    const int nchunk = (N + 63) / 64;
    const int aggblk = ((nchunk + 1) / 2) * 8;

    wconv_kernel<<<64, 256, 0, stream>>>(W1, W2, wt1, wt2, h, N);
    partition_kernel<<<NCP, 256, 0, stream>>>(er, ec, prs, srcp, rof, srof, E, cpb, NR);
    colhist_kernel<<<dim3(NC, NR), 256, 0, stream>>>(prs, rof, pcol, N, cpb);
    deghist_kernel<<<dim3(NCD, NR), 256, 0, stream>>>(srcp, srof, pdeg, N, cpb, GPD);
    chunk_scan_kernel<<<csblk, 256, 0, stream>>>(pcol, pdeg, tot, dis, N, NC, NCD);
    bsum_kernel<<<nblk, 256, 0, stream>>>(tot, bsum, N);
    scan_bsum_kernel<<<1, 1024, 0, stream>>>(bsum, nblk);
    rowptr_kernel<<<nblk, 256, 0, stream>>>(tot, bsum, rp, csr, N);
    fill_kernel<<<dim3(NC, NR), 256, 0, stream>>>(prs, rof, rp, pcol, csr, N, cpb);

    // layer 1: h' = dis.*bf16(x@W1) ; d_out = relu(agg(h') + b1)
    gemm_xw<<<(N + 63) / 64, 256, 0, stream>>>(x, wt1, dis, h, N);
    agg_kernel<<<aggblk, 256, 0, stream>>>(h, dis, rp, csr, b1, out, N, 1);

    // layer 2: h' = dis.*bf16(d_out@W2) ; d_out = agg(h') + b2
    gemm_xw<<<(N + 63) / 64, 256, 0, stream>>>(out, wt2, dis, h, N);
    agg_kernel<<<aggblk, 256, 0, stream>>>(h, dis, rp, csr, b2, out, N, 0);
}